// Round 2
// baseline (461.114 us; speedup 1.0000x reference)
//
#include <hip/hip_runtime.h>

// LoRA attention: B=4, S=2048, E=1024, R=16, fp32 in/out.
// R7 changes vs R6:
//  - R6's hot dispatch (attn P@V) ran on a HALF-EMPTY chip: 128 wg of 8 waves
//    on 256 CUs (Occupancy 10.4%, chip MfmaUtil 17.6% but ~36% on active CUs).
//    V-proj and final gemm had the same 128-wg problem. Added a BN=128 tile
//    variant (256x128, 96 KB LDS) -> 256 wg for those three gemms.
//  - ds_reads spread across all 4 phases (m201-faithful: 4-8 reads/phase,
//    2 barriers/phase) instead of 24 reads front-loaded into ph0/ph1:
//    phA{ks0 aLo + b, stage B(t+1)h0} phB{ks0 aHi, stage B(t+1)h1}
//    phC{ks1 aLo + b} phD{ks1 aHi}; then lgkmcnt(0)+barrier; stage A(t+2).
//    Live fragments 24 -> 12 short8 (less VGPR pressure -> no scratch traffic
//    that would pollute vmcnt accounting).
// Carried: counted s_waitcnt vmcnt(4) at tile entry (never 0 in main loop),
// setprio(1) around MFMA clusters, fragment-major LDS layout (0 bank
// conflicts), XCD-aware swizzle, k-clamped dummy stages for uniform vmcnt.
// Race-freedom per tile t (cur = t&1):
//  - entry: vmcnt(4)+barrier => tile t fully landed (4 newest in-flight loads
//    are A(t+1) halves, staged at end of tile t-1 into buf cur^1).
//  - phA/phB stage B(t+1) into buf cur^1 (its old B was fully read by tile
//    t-1; reads drained by t-1's trailing lgkmcnt(0)+barrier).
//  - trailing lgkmcnt(0)+barrier => ALL waves' reads of buf cur complete;
//    then A(t+2) staged into buf cur (same parity as t+2). Dummy restages on
//    the last tiles land in buffers never read again.

#define S_LEN 2048
#define E_DIM 1024

typedef __attribute__((ext_vector_type(8))) short short8;
typedef __attribute__((ext_vector_type(4))) float floatx4;

__device__ __forceinline__ unsigned short f2bf(float f) {
  union { float f; unsigned int u; } x; x.f = f;
  return (unsigned short)((x.u + 0x7fffu + ((x.u >> 16) & 1u)) >> 16);  // RNE
}
__device__ __forceinline__ float bf2f(unsigned short h) {
  union { unsigned int u; float f; } x; x.u = ((unsigned int)h) << 16;
  return x.f;
}

__device__ __forceinline__ void gld_lds16(const unsigned short* g, unsigned short* l) {
  __builtin_amdgcn_global_load_lds(
      (const __attribute__((address_space(1))) unsigned int*)(const void*)g,
      (__attribute__((address_space(3))) unsigned int*)(void*)l,
      16, 0, 0);
}

// C[m][n] = scale * (sum_k A[m][k]*B[n][k]  (+ LoRA: sum_r LA[m][r]*LB[n][r]))
// BM=256 x BN(256|128) tile, BK=64, 512 threads (8 waves, 2M x 4N), per-wave
// output 128 x BN/4. LDS half-tile fragment-major: 16B chunk (row,kc) at
// chunk index (row>>4)*128 + kc*16 + (row&15); fragment (rowgroup g, ks) is
// ds_read_b128 at chunk g*128 + ks*64 + lane (lane-contiguous, 0 conflicts).
template<bool LORA, bool OUTF32, bool OWNM, int BN>
__global__ __launch_bounds__(512, 2) void gemm256(
    const unsigned short* __restrict__ A, const unsigned short* __restrict__ B,
    void* __restrict__ Cv,
    const unsigned short* __restrict__ LA, const unsigned short* __restrict__ LB,
    long lda, long ldb, long ldc, int K, float scale,
    long batA, long batB, long batC, long batLA, long batLB) {
  constexpr int BNH = BN / 2;       // rows per B half (128 | 64)
  constexpr int BCH = BNH * 8;      // 16B chunks per B half (1024 | 512)
  constexpr int JW  = BN / 64;      // B fragments per wave (4 | 2)
  __shared__ alignas(16) unsigned short As[2][2][8192];     // [buf][half][128*64]
  __shared__ alignas(16) unsigned short Bs[2][2][BCH * 8];  // [buf][half][BNH*64]

  const int tid  = threadIdx.x;
  const int wave = tid >> 6, lane = tid & 63;
  const int quad = lane >> 4, l16 = lane & 15;
  const int wr = wave >> 2, wc = wave & 3;  // 2x4 waves
  const int bg = (wc & 1) * JW;             // B row-group base within its half

  // XCD-aware swizzle: xcd = flat%8 owns a chunk of the M (or N) tiles and
  // sweeps the other dimension fastest. Per-z wg counts are multiples of 8.
  const int Nx = (int)gridDim.x, Ny = (int)gridDim.y;
  const int wg2 = (int)blockIdx.x + Nx * (int)blockIdx.y;
  const int xcd = wg2 & 7, ii = wg2 >> 3;
  int bx, by;
  if constexpr (OWNM) {
    const int lg = 31 - __clz(Nx);
    by = xcd * (Ny >> 3) + (ii >> lg);
    bx = ii & (Nx - 1);
  } else {
    const int lg = 31 - __clz(Ny);
    bx = xcd * (Nx >> 3) + (ii >> lg);
    by = ii & (Ny - 1);
  }
  const long m0 = (long)by * 256;
  const long n0 = (long)bx * BN;
  const unsigned short* Az = A + (long)blockIdx.z * batA;
  const unsigned short* Bz = B + (long)blockIdx.z * batB;

  floatx4 acc[8][JW];
#pragma unroll
  for (int i = 0; i < 8; ++i)
#pragma unroll
    for (int j = 0; j < JW; ++j) acc[i][j] = (floatx4){0.f, 0.f, 0.f, 0.f};

  // Stage source mapping for chunk c = tid (+512): rowInHalf = ((c>>7)<<4)|(c&15),
  // koff = ((c>>4)&7)*8; dest chunk index == c (fragment-major identity).
  const int c0r = ((tid >> 7) << 4) | (tid & 15);
  const int c0k = ((tid >> 4) & 7) << 3;
  const unsigned short* a0 = Az + (m0 + c0r) * lda + c0k;
  const unsigned short* b0 = Bz + (n0 + c0r) * ldb + c0k;

#define STG_A(bf, h, k0)                                                    \
  do {                                                                      \
    gld_lds16(a0 + (long)((h) * 128) * lda + (k0), &As[bf][h][tid * 8]);    \
    gld_lds16(a0 + (long)((h) * 128 + 64) * lda + (k0),                     \
              &As[bf][h][4096 + tid * 8]);                                  \
  } while (0)
#define STG_B(bf, h, k0)                                                    \
  do {                                                                      \
    gld_lds16(b0 + (long)((h) * BNH) * ldb + (k0), &Bs[bf][h][tid * 8]);    \
    if constexpr (BN == 256)                                                \
      gld_lds16(b0 + (long)((h) * BNH + 64) * ldb + (k0),                   \
                &Bs[bf][h][4096 + tid * 8]);                                \
  } while (0)

  // prologue: tile 0 (A+B) into buf0, tile 1 A-halves into buf1.
  STG_A(0, 0, 0); STG_A(0, 1, 0);
  STG_B(0, 0, 0); STG_B(0, 1, 0);
  STG_A(1, 0, 64); STG_A(1, 1, 64);

  const int NT = K >> 6;
#pragma unroll 2
  for (int t = 0; t < NT; ++t) {
    const int cur = t & 1;
    const int kB = (t + 1 < NT ? t + 1 : NT - 1) << 6;
    const int kA = (t + 2 < NT ? t + 2 : NT - 1) << 6;
    const unsigned short* ra = &As[cur][wr][0];
    const unsigned short* rb = &Bs[cur][wc >> 1][0];

    // tile entry: 4 newest outstanding loads are A(t+1); everything older
    // (incl. this tile's B) has landed.
    asm volatile("s_waitcnt vmcnt(4)\n\ts_barrier" ::: "memory");

    short8 aLo[4], aHi[4], bb[JW];
    // ---- phase A: ks=0, A rowgroups 0-3 + all B; stage B(t+1) half0
#pragma unroll
    for (int i = 0; i < 4; ++i)
      aLo[i] = *(const short8*)(ra + (i * 128 + lane) * 8);
#pragma unroll
    for (int j = 0; j < JW; ++j)
      bb[j] = *(const short8*)(rb + ((bg + j) * 128 + lane) * 8);
    STG_B(cur ^ 1, 0, kB);
    asm volatile("s_barrier" ::: "memory");
    __builtin_amdgcn_s_setprio(1);
#pragma unroll
    for (int i = 0; i < 4; ++i)
#pragma unroll
      for (int j = 0; j < JW; ++j)
        acc[i][j] = __builtin_amdgcn_mfma_f32_16x16x32_bf16(aLo[i], bb[j], acc[i][j], 0, 0, 0);
    __builtin_amdgcn_s_setprio(0);
    asm volatile("s_barrier" ::: "memory");

    // ---- phase B: ks=0, A rowgroups 4-7; stage B(t+1) half1
#pragma unroll
    for (int i = 0; i < 4; ++i)
      aHi[i] = *(const short8*)(ra + ((i + 4) * 128 + lane) * 8);
    STG_B(cur ^ 1, 1, kB);
    asm volatile("s_barrier" ::: "memory");
    __builtin_amdgcn_s_setprio(1);
#pragma unroll
    for (int i = 0; i < 4; ++i)
#pragma unroll
      for (int j = 0; j < JW; ++j)
        acc[i + 4][j] = __builtin_amdgcn_mfma_f32_16x16x32_bf16(aHi[i], bb[j], acc[i + 4][j], 0, 0, 0);
    __builtin_amdgcn_s_setprio(0);
    asm volatile("s_barrier" ::: "memory");

    // ---- phase C: ks=1, A rowgroups 0-3 + all B
#pragma unroll
    for (int i = 0; i < 4; ++i)
      aLo[i] = *(const short8*)(ra + (i * 128 + 64 + lane) * 8);
#pragma unroll
    for (int j = 0; j < JW; ++j)
      bb[j] = *(const short8*)(rb + ((bg + j) * 128 + 64 + lane) * 8);
    asm volatile("s_barrier" ::: "memory");
    __builtin_amdgcn_s_setprio(1);
#pragma unroll
    for (int i = 0; i < 4; ++i)
#pragma unroll
      for (int j = 0; j < JW; ++j)
        acc[i][j] = __builtin_amdgcn_mfma_f32_16x16x32_bf16(aLo[i], bb[j], acc[i][j], 0, 0, 0);
    __builtin_amdgcn_s_setprio(0);
    asm volatile("s_barrier" ::: "memory");

    // ---- phase D: ks=1, A rowgroups 4-7
#pragma unroll
    for (int i = 0; i < 4; ++i)
      aHi[i] = *(const short8*)(ra + ((i + 4) * 128 + 64 + lane) * 8);
    asm volatile("s_barrier" ::: "memory");
    __builtin_amdgcn_s_setprio(1);
#pragma unroll
    for (int i = 0; i < 4; ++i)
#pragma unroll
      for (int j = 0; j < JW; ++j)
        acc[i + 4][j] = __builtin_amdgcn_mfma_f32_16x16x32_bf16(aHi[i], bb[j], acc[i + 4][j], 0, 0, 0);
    __builtin_amdgcn_s_setprio(0);

    // all reads of buf[cur] drained chip-wide -> stage A(t+2) into cur
    asm volatile("s_waitcnt lgkmcnt(0)\n\ts_barrier" ::: "memory");
    STG_A(cur, 0, kA);
    STG_A(cur, 1, kA);
  }

  if constexpr (LORA) {
    asm volatile("s_waitcnt vmcnt(0)" ::: "memory");  // pending dummy stages
    __syncthreads();
    const unsigned short* LAz = LA + (long)blockIdx.z * batLA;
    const unsigned short* LBz = LB + (long)blockIdx.z * batLB;
    // Fill buf0 with LoRA operands, same fragment-major layout:
    // kc 0..1 = ranks 0..15, kc >= 2 zero (one MFMA at ks=0 covers k 0..31).
#pragma unroll
    for (int cc = 0; cc < 4; ++cc) {  // A: 2048 chunks
      const int c = cc * 512 + tid;
      const int h = c >> 10, ci = c & 1023;
      const int kc = (ci >> 4) & 7;
      const int row = h * 128 + ((ci >> 7) << 4) + (ci & 15);
      uint4 va;
      if (kc < 2) va = *(const uint4*)(LAz + (m0 + row) * 16 + kc * 8);
      else { va.x = va.y = va.z = va.w = 0u; }
      *(uint4*)(&As[0][h][ci * 8]) = va;
    }
#pragma unroll
    for (int cc = 0; cc < (2 * BCH) / 512; ++cc) {  // B: 2*BCH chunks
      const int c = cc * 512 + tid;
      const int h = c / BCH, ci = c % BCH;
      const int kc = (ci >> 4) & 7;
      const int row = h * BNH + ((ci >> 7) << 4) + (ci & 15);
      uint4 vb_;
      if (kc < 2) vb_ = *(const uint4*)(LBz + (n0 + row) * 16 + kc * 8);
      else { vb_.x = vb_.y = vb_.z = vb_.w = 0u; }
      *(uint4*)(&Bs[0][h][ci * 8]) = vb_;
    }
    __syncthreads();
    short8 a2[8], b2[JW];
#pragma unroll
    for (int i = 0; i < 8; ++i)
      a2[i] = *(const short8*)(&As[0][wr][(i * 128 + lane) * 8]);
#pragma unroll
    for (int j = 0; j < JW; ++j)
      b2[j] = *(const short8*)(&Bs[0][wc >> 1][((bg + j) * 128 + lane) * 8]);
#pragma unroll
    for (int i = 0; i < 8; ++i)
#pragma unroll
      for (int j = 0; j < JW; ++j)
        acc[i][j] = __builtin_amdgcn_mfma_f32_16x16x32_bf16(a2[i], b2[j], acc[i][j], 0, 0, 0);
  } else {
    // drain in-flight LDS-DMA before the block can retire
    asm volatile("s_waitcnt vmcnt(0)" ::: "memory");
  }

#pragma unroll
  for (int i = 0; i < 8; ++i) {
    const long row = m0 + wr * 128 + i * 16 + quad * 4;
#pragma unroll
    for (int j = 0; j < JW; ++j) {
      const long col = n0 + wc * (16 * JW) + j * 16 + l16;
#pragma unroll
      for (int rr = 0; rr < 4; ++rr) {
        float val = acc[i][j][rr] * scale;
        if constexpr (OUTF32)
          ((float*)Cv)[(long)blockIdx.z * batC + (row + rr) * ldc + col] = val;
        else
          ((unsigned short*)Cv)[(long)blockIdx.z * batC + (row + rr) * ldc + col] = f2bf(val);
      }
    }
  }
#undef STG_A
#undef STG_B
}

__device__ __forceinline__ uint4 pack8(const float* x) {
  float4 a = *(const float4*)x;
  float4 b = *(const float4*)(x + 4);
  uint4 o;
  o.x = (unsigned int)f2bf(a.x) | ((unsigned int)f2bf(a.y) << 16);
  o.y = (unsigned int)f2bf(a.z) | ((unsigned int)f2bf(a.w) << 16);
  o.z = (unsigned int)f2bf(b.x) | ((unsigned int)f2bf(b.y) << 16);
  o.w = (unsigned int)f2bf(b.z) | ((unsigned int)f2bf(b.w) << 16);
  return o;
}

// pure fp32->bf16 convert of q/k/v. grid (512, 3), 16384 elems/block.
__global__ __launch_bounds__(256) void prep_qkv(
    const float* __restrict__ q, const float* __restrict__ k, const float* __restrict__ v,
    unsigned short* __restrict__ qb, unsigned short* __restrict__ kb,
    unsigned short* __restrict__ vb) {
  const float* X; unsigned short* Y;
  if (blockIdx.y == 0)      { X = q; Y = qb; }
  else if (blockIdx.y == 1) { X = k; Y = kb; }
  else                      { X = v; Y = vb; }
  const int tid = threadIdx.x;
  const long blk = (long)blockIdx.x * 16384;
#pragma unroll
  for (int it = 0; it < 8; ++it) {
    const long idx = blk + it * 2048 + tid * 8;
    *(uint4*)(Y + idx) = pack8(X + idx);
  }
}

// all weight converts in one dispatch. grid (512, 5):
//  y<4: big 1024x1024 matrices (Wq,Wk,Wv,Wo), x in [0,512)
//  y==4: six 16k matrices (QB,KB,VB,QA,KA,VA), x in [0,48): mat=x>>3, sub=x&7
__global__ __launch_bounds__(256) void cvt_all(
    const float* __restrict__ Wq, const float* __restrict__ Wk,
    const float* __restrict__ Wv, const float* __restrict__ Wo,
    const float* __restrict__ QB, const float* __restrict__ KB, const float* __restrict__ VB,
    const float* __restrict__ QA, const float* __restrict__ KA, const float* __restrict__ VA,
    unsigned short* __restrict__ wqb, unsigned short* __restrict__ wkb,
    unsigned short* __restrict__ wvb, unsigned short* __restrict__ wob,
    unsigned short* __restrict__ Bqb, unsigned short* __restrict__ Bkb, unsigned short* __restrict__ Bvb,
    unsigned short* __restrict__ Aqb, unsigned short* __restrict__ Akb, unsigned short* __restrict__ Avb) {
  if (blockIdx.y < 4) {
    const float* x; unsigned short* y;
    switch (blockIdx.y) {
      case 0: x = Wq; y = wqb; break;
      case 1: x = Wk; y = wkb; break;
      case 2: x = Wv; y = wvb; break;
      default: x = Wo; y = wob; break;
    }
    const long i = ((long)blockIdx.x * 256 + threadIdx.x) * 8;
    *(uint4*)(y + i) = pack8(x + i);
  } else {
    if (blockIdx.x >= 48) return;
    const int mat = blockIdx.x >> 3, sub = blockIdx.x & 7;
    const float* x; unsigned short* y;
    switch (mat) {
      case 0: x = QB; y = Bqb; break;
      case 1: x = KB; y = Bkb; break;
      case 2: x = VB; y = Bvb; break;
      case 3: x = QA; y = Aqb; break;
      case 4: x = KA; y = Akb; break;
      default: x = VA; y = Avb; break;
    }
    const long i = ((long)sub * 256 + threadIdx.x) * 8;
    *(uint4*)(y + i) = pack8(x + i);
  }
}

// T[8192][16] = Xb @ Am^T via MFMA. grid (128, 3): 64 rows/block, 16/wave.
__global__ __launch_bounds__(256) void lora_t_mfma(
    const unsigned short* __restrict__ qb, const unsigned short* __restrict__ kb,
    const unsigned short* __restrict__ vb,
    const unsigned short* __restrict__ Aq, const unsigned short* __restrict__ Ak,
    const unsigned short* __restrict__ Av,
    unsigned short* __restrict__ Tq, unsigned short* __restrict__ Tk,
    unsigned short* __restrict__ Tv) {
  const unsigned short* X; const unsigned short* Am; unsigned short* T;
  if (blockIdx.y == 0)      { X = qb; Am = Aq; T = Tq; }
  else if (blockIdx.y == 1) { X = kb; Am = Ak; T = Tk; }
  else                      { X = vb; Am = Av; T = Tv; }
  const int tid = threadIdx.x, wave = tid >> 6, lane = tid & 63;
  const int quad = lane >> 4, l16 = lane & 15;
  const long m0 = (long)blockIdx.x * 64 + wave * 16;
  floatx4 acc = (floatx4){0.f, 0.f, 0.f, 0.f};
  const unsigned short* xp = X + (m0 + l16) * 1024 + quad * 8;
  const unsigned short* ap = Am + (long)l16 * 1024 + quad * 8;
#pragma unroll 4
  for (int k0 = 0; k0 < 1024; k0 += 32) {
    short8 af = *(const short8*)(xp + k0);
    short8 bf = *(const short8*)(ap + k0);
    acc = __builtin_amdgcn_mfma_f32_16x16x32_bf16(af, bf, acc, 0, 0, 0);
  }
#pragma unroll
  for (int rr = 0; rr < 4; ++rr)
    T[(m0 + quad * 4 + rr) * 16 + l16] = f2bf(acc[rr]);
}

// in-place row softmax over 2048 bf16 scores; one block per row
__global__ __launch_bounds__(256) void softmax_kernel(unsigned short* __restrict__ S) {
  const long base = (long)blockIdx.x * 2048;
  const int tid = threadIdx.x;
  const int lane = tid & 63, wave = tid >> 6;
  __shared__ float redm[4], reds[4];
  uint4 raw = *(const uint4*)(S + base + tid * 8);
  unsigned int w[4] = {raw.x, raw.y, raw.z, raw.w};
  float v[8];
#pragma unroll
  for (int i = 0; i < 4; ++i) {
    v[2 * i]     = bf2f((unsigned short)(w[i] & 0xffffu));
    v[2 * i + 1] = bf2f((unsigned short)(w[i] >> 16));
  }
  float m = v[0];
#pragma unroll
  for (int i = 1; i < 8; ++i) m = fmaxf(m, v[i]);
  for (int off = 32; off >= 1; off >>= 1) m = fmaxf(m, __shfl_xor(m, off, 64));
  if (lane == 0) redm[wave] = m;
  __syncthreads();
  m = fmaxf(fmaxf(redm[0], redm[1]), fmaxf(redm[2], redm[3]));
  float e[8], s = 0.f;
#pragma unroll
  for (int i = 0; i < 8; ++i) { e[i] = __expf(v[i] - m); s += e[i]; }
  for (int off = 32; off >= 1; off >>= 1) s += __shfl_xor(s, off, 64);
  if (lane == 0) reds[wave] = s;
  __syncthreads();
  s = reds[0] + reds[1] + reds[2] + reds[3];
  const float inv = 1.0f / s;
  uint4 o;
  o.x = (unsigned int)f2bf(e[0] * inv) | ((unsigned int)f2bf(e[1] * inv) << 16);
  o.y = (unsigned int)f2bf(e[2] * inv) | ((unsigned int)f2bf(e[3] * inv) << 16);
  o.z = (unsigned int)f2bf(e[4] * inv) | ((unsigned int)f2bf(e[5] * inv) << 16);
  o.w = (unsigned int)f2bf(e[6] * inv) | ((unsigned int)f2bf(e[7] * inv) << 16);
  *(uint4*)(S + base + tid * 8) = o;
}

extern "C" void kernel_launch(void* const* d_in, const int* in_sizes, int n_in,
                              void* d_out, int out_size, void* d_ws, size_t ws_size,
                              hipStream_t stream) {
  const float* q  = (const float*)d_in[0];
  const float* k  = (const float*)d_in[1];
  const float* v  = (const float*)d_in[2];
  const float* Wq = (const float*)d_in[3];
  const float* Wk = (const float*)d_in[4];
  const float* Wv = (const float*)d_in[5];
  const float* QA = (const float*)d_in[6];
  const float* QB = (const float*)d_in[7];
  const float* KA = (const float*)d_in[8];
  const float* KB = (const float*)d_in[9];
  const float* VA = (const float*)d_in[10];
  const float* VB = (const float*)d_in[11];
  const float* Wo = (const float*)d_in[12];

  unsigned short* W = (unsigned short*)d_ws;
  const long SEe = (long)8192 * 1024;  // 8388608
  unsigned short* qb  = W;             // dead after Q-proj -> scores low half
  unsigned short* kb  = W + SEe;
  unsigned short* vb  = W + 2 * SEe;   // dead after V-proj -> attn buffer
  unsigned short* Qp  = W + 3 * SEe;
  unsigned short* Kp  = W + 4 * SEe;
  unsigned short* VT  = W + 5 * SEe;   // [1024][8192] = V^T
  unsigned short* wqb = W + 6 * SEe;
  unsigned short* wkb = wqb + 1048576;
  unsigned short* wvb = wkb + 1048576;
  unsigned short* wob = wvb + 1048576;
  unsigned short* Bqb = wob + 1048576;
  unsigned short* Bkb = Bqb + 16384;
  unsigned short* Bvb = Bkb + 16384;
  unsigned short* Aqb = Bvb + 16384;
  unsigned short* Akb = Aqb + 16384;
  unsigned short* Avb = Akb + 16384;
  unsigned short* Tq  = Avb + 16384;   // [8192][16]
  unsigned short* Tk  = Tq + 131072;
  unsigned short* Tv  = Tk + 131072;
  unsigned short* scores = W;          // [4][2048][2048] bf16, aliases qb+kb
  unsigned short* attn   = vb;         // [8192][1024] bf16, aliases vb

  dim3 blk(256, 1, 1), blk5(512, 1, 1);
  prep_qkv<<<dim3(512, 3, 1), blk, 0, stream>>>(q, k, v, qb, kb, vb);
  cvt_all<<<dim3(512, 5, 1), blk, 0, stream>>>(Wq, Wk, Wv, Wo, QB, KB, VB, QA, KA, VA,
                                               wqb, wkb, wvb, wob, Bqb, Bkb, Bvb, Aqb, Akb, Avb);
  lora_t_mfma<<<dim3(128, 3, 1), blk, 0, stream>>>(qb, kb, vb, Aqb, Akb, Avb, Tq, Tk, Tv);

  // Q = qb@Wq^T + Tq@Bq^T ; K likewise (z batches; M=8192,N=1024,K=1024)
  gemm256<true, false, true, 256><<<dim3(4, 32, 2), blk5, 0, stream>>>(
      qb, wqb, Qp, Tq, Bqb, 1024, 1024, 1024, 1024, 1.0f,
      SEe, 1048576, SEe, 131072, 16384);
  // VT = Wv@vb^T + Bv@Tv^T  (M=1024,N=8192): OWNN, BN=128 -> 256 wg
  gemm256<true, false, false, 128><<<dim3(64, 4, 1), blk5, 0, stream>>>(
      wvb, vb, VT, Bvb, Tv, 1024, 1024, 8192, 1024, 1.0f, 0, 0, 0, 0, 0);
  // scores = Qp@Kp^T / 32   (batched, M=N=2048,K=1024)
  gemm256<false, false, true, 256><<<dim3(8, 8, 4), blk5, 0, stream>>>(
      Qp, Kp, scores, nullptr, nullptr, 1024, 1024, 2048, 1024, 0.03125f,
      (long)S_LEN * E_DIM, (long)S_LEN * E_DIM, (long)S_LEN * S_LEN, 0, 0);
  softmax_kernel<<<8192, blk, 0, stream>>>(scores);
  // attn_out = P@V = P@(VT)^T  (batched, M=2048,N=1024,K=2048), BN=128 -> 256 wg
  gemm256<false, false, true, 128><<<dim3(8, 8, 4), blk5, 0, stream>>>(
      scores, VT, attn, nullptr, nullptr, 2048, 8192, 1024, 2048, 1.0f,
      (long)S_LEN * S_LEN, (long)S_LEN, (long)S_LEN * E_DIM, 0, 0);
  // final = attn@Wo^T -> fp32 d_out  (M=8192,N=1024,K=1024), BN=128 -> 256 wg
  gemm256<false, true, true, 128><<<dim3(8, 32, 1), blk5, 0, stream>>>(
      attn, wob, d_out, nullptr, nullptr, 1024, 1024, 1024, 1024, 1.0f, 0, 0, 0, 0, 0);
}

// Round 4
// 425.876 us; speedup vs baseline: 1.0827x; 1.0827x over previous
//
#include <hip/hip_runtime.h>

// LoRA attention: B=4, S=2048, E=1024, R=16, fp32 in/out.
// R9 == R8 resubmitted (R8's bench was an infra failure: "container failed
// twice", no profile; kernel re-audited for hang/fault paths — none found:
// uniform barrier counts, exact vmcnt arithmetic, all bounds in range,
// LDS 144KB <= 160KB, no spill at measured 88 VGPR structure).
// R8 changes vs R7 (which regressed; R6/R7 post-mortem):
//  - Hot gemm ran 76us under BOTH R6(128wg,256^2) and R7(256wg,256x128):
//    per-CU limit, not wg count. Per-tile LDS-pipe time (reads 8wx20-24 b128
//    x12cyc + 48-64KB gld_lds writes ~ 2500-3100cyc) dominates the measured
//    5700cyc/tile; rest is 8 barriers/tile serialization.
//  - Wave grid 2Mx4N -> 4Mx2N (64x64/wave): duplicate LDS reads minimized
//    (A read by 2 waves not 4; 16 b128/wave/tile instead of 20).
//  - ONE barrier per K-tile: entry "vmcnt(6) lgkmcnt(0); s_barrier"; all 16
//    reads front-loaded; compiler's counted lgkmcnt pipelines reads->MFMA
//    (R6-style front-load beat R7's per-phase reads).
//  - Triple-buffered LDS (3 x 48KB = 144KB): tile t's 6 loads issued during
//    tile t-2 -> 2-tile prefetch depth; vmcnt(6) at entry = exactly tile
//    t+1's loads in flight. Never vmcnt(0) in the main loop.
//  - BN=128 for ALL gemms -> 256-512 wg each (full chip).
// Race-freedom: entry of tile t waits per-wave lgkmcnt(0) then barriers =>
// all waves' reads of buf[(t-1)%3] done => staging tile t+2 into that buffer
// during tile t is safe. Entry vmcnt(6) => tile t's loads (issued during
// t-2) landed. Dummy clamped stages on last 2 tiles keep vmcnt uniform and
// target buffers that are never read again.

#define S_LEN 2048
#define E_DIM 1024

typedef __attribute__((ext_vector_type(8))) short short8;
typedef __attribute__((ext_vector_type(4))) float floatx4;

__device__ __forceinline__ unsigned short f2bf(float f) {
  union { float f; unsigned int u; } x; x.f = f;
  return (unsigned short)((x.u + 0x7fffu + ((x.u >> 16) & 1u)) >> 16);  // RNE
}
__device__ __forceinline__ float bf2f(unsigned short h) {
  union { unsigned int u; float f; } x; x.u = ((unsigned int)h) << 16;
  return x.f;
}

__device__ __forceinline__ void gld_lds16(const unsigned short* g, unsigned short* l) {
  __builtin_amdgcn_global_load_lds(
      (const __attribute__((address_space(1))) unsigned int*)(const void*)g,
      (__attribute__((address_space(3))) unsigned int*)(void*)l,
      16, 0, 0);
}

// C[m][n] = scale * (sum_k A[m][k]*B[n][k]  (+ LoRA: sum_r LA[m][r]*LB[n][r]))
// BM=256 x BN=128, BK=64, 512 threads (8 waves, 4M x 2N), 64x64 out per wave.
// LDS fragment-major per 64-row group: 16B chunk (row,kc) at chunk index
// (row>>4)*128 + kc*16 + (row&15) within its group; fragment (16-row grp i,
// ks) = ds_read_b128 at chunk i*128 + ks*64 + lane (lane-contiguous, 0 bank
// conflicts). gld_lds dest is linear (base + tid*16), source pre-swizzled.
template<bool LORA, bool OUTF32, bool OWNM>
__global__ __launch_bounds__(512, 2) void gemm3b(
    const unsigned short* __restrict__ A, const unsigned short* __restrict__ B,
    void* __restrict__ Cv,
    const unsigned short* __restrict__ LA, const unsigned short* __restrict__ LB,
    long lda, long ldb, long ldc, int K, float scale,
    long batA, long batB, long batC, long batLA, long batLB) {
  __shared__ alignas(16) unsigned short As[3][16384];  // 3 bufs x (256 x 64)
  __shared__ alignas(16) unsigned short Bs[3][8192];   // 3 bufs x (128 x 64)

  const int tid  = threadIdx.x;
  const int wave = tid >> 6, lane = tid & 63;
  const int quad = lane >> 4, l16 = lane & 15;
  const int wr = wave >> 1, wc = wave & 1;  // 4x2 waves, each 64x64

  // XCD-aware swizzle: xcd = flat%8 owns a chunk of the M (or N) tiles and
  // sweeps the other dimension fastest. Per-z wg counts are multiples of 8.
  const int Nx = (int)gridDim.x, Ny = (int)gridDim.y;
  const int wg2 = (int)blockIdx.x + Nx * (int)blockIdx.y;
  const int xcd = wg2 & 7, ii = wg2 >> 3;
  int bx, by;
  if constexpr (OWNM) {
    const int lg = 31 - __clz(Nx);
    by = xcd * (Ny >> 3) + (ii >> lg);
    bx = ii & (Nx - 1);
  } else {
    const int lg = 31 - __clz(Ny);
    bx = xcd * (Nx >> 3) + (ii >> lg);
    by = ii & (Ny - 1);
  }
  const long m0 = (long)by * 256;
  const long n0 = (long)bx * 128;
  const unsigned short* Az = A + (long)blockIdx.z * batA;
  const unsigned short* Bz = B + (long)blockIdx.z * batB;

  floatx4 acc[4][4];
#pragma unroll
  for (int i = 0; i < 4; ++i)
#pragma unroll
    for (int j = 0; j < 4; ++j) acc[i][j] = (floatx4){0.f, 0.f, 0.f, 0.f};

  // Stage source mapping for chunk c = tid: rowInGroup = ((c>>7)<<4)|(c&15),
  // koff = ((c>>4)&7)*8; dest chunk index == c (fragment-major identity).
  const int c0r = ((tid >> 7) << 4) | (tid & 15);
  const int c0k = ((tid >> 4) & 7) << 3;
  const unsigned short* a0 = Az + (m0 + c0r) * lda + c0k;
  const unsigned short* b0 = Bz + (n0 + c0r) * ldb + c0k;

#define STG_A(bf, k0)                                                   \
  do {                                                                  \
    unsigned short* d = &As[bf][tid * 8];                               \
    gld_lds16(a0 + (k0), d);                                            \
    gld_lds16(a0 + 64 * lda + (k0), d + 4096);                          \
    gld_lds16(a0 + 128 * lda + (k0), d + 8192);                         \
    gld_lds16(a0 + 192 * lda + (k0), d + 12288);                        \
  } while (0)
#define STG_B(bf, k0)                                                   \
  do {                                                                  \
    unsigned short* d = &Bs[bf][tid * 8];                               \
    gld_lds16(b0 + (k0), d);                                            \
    gld_lds16(b0 + 64 * ldb + (k0), d + 4096);                          \
  } while (0)

  // prologue: tile 0 -> buf0, tile 1 -> buf1 (12 loads total).
  STG_A(0, 0); STG_B(0, 0);
  STG_A(1, 64); STG_B(1, 64);

  const int NT = K >> 6;
  int cur = 0;
  for (int t = 0; t < NT; ++t) {
    const int s2 = (cur == 0) ? 2 : cur - 1;  // (cur+2)%3
    const int kA = (t + 2 < NT ? t + 2 : NT - 1) << 6;
    const unsigned short* ra = &As[cur][0];
    const unsigned short* rb = &Bs[cur][0];

    // entry: per-wave drain of our prev-tile ds_reads, wait tile t's 6 loads
    // (issued during t-2; t+1's 6 remain in flight), then sync.
    asm volatile("s_waitcnt vmcnt(6) lgkmcnt(0)\n\ts_barrier" ::: "memory");

    short8 af[4][2], bf_[4][2];
#pragma unroll
    for (int i = 0; i < 4; ++i) {
      af[i][0] = *(const short8*)(ra + ((wr * 4 + i) * 128 + lane) * 8);
      af[i][1] = *(const short8*)(ra + ((wr * 4 + i) * 128 + 64 + lane) * 8);
    }
#pragma unroll
    for (int j = 0; j < 4; ++j) {
      bf_[j][0] = *(const short8*)(rb + ((wc * 4 + j) * 128 + lane) * 8);
      bf_[j][1] = *(const short8*)(rb + ((wc * 4 + j) * 128 + 64 + lane) * 8);
    }
    // stage tile t+2 into buf s2 (== buf[(t-1)%3], drained by this entry)
    STG_A(s2, kA);
    STG_B(s2, kA);

    __builtin_amdgcn_s_setprio(1);
#pragma unroll
    for (int ks = 0; ks < 2; ++ks)
#pragma unroll
      for (int i = 0; i < 4; ++i)
#pragma unroll
        for (int j = 0; j < 4; ++j)
          acc[i][j] = __builtin_amdgcn_mfma_f32_16x16x32_bf16(
              af[i][ks], bf_[j][ks], acc[i][j], 0, 0, 0);
    __builtin_amdgcn_s_setprio(0);

    cur = (cur == 2) ? 0 : cur + 1;
  }

  if constexpr (LORA) {
    // drain all in-flight LDS-DMA (incl. dummies), then sync all waves
    asm volatile("s_waitcnt vmcnt(0)" ::: "memory");
    __syncthreads();
    const unsigned short* LAz = LA + (long)blockIdx.z * batLA;
    const unsigned short* LBz = LB + (long)blockIdx.z * batLB;
    // Fill buf0 with LoRA operands in the same fragment-major layout:
    // kc 0..1 = ranks 0..15, kc >= 2 zero (one MFMA at ks=0 covers k 0..31).
#pragma unroll
    for (int cc = 0; cc < 4; ++cc) {  // A: 2048 chunks
      const int c = cc * 512 + tid;
      const int kc = (c >> 4) & 7;
      const int row = (c >> 7) * 16 + (c & 15);
      uint4 va;
      if (kc < 2) va = *(const uint4*)(LAz + (m0 + row) * 16 + kc * 8);
      else { va.x = va.y = va.z = va.w = 0u; }
      *(uint4*)(&As[0][c * 8]) = va;
    }
#pragma unroll
    for (int cc = 0; cc < 2; ++cc) {  // B: 1024 chunks
      const int c = cc * 512 + tid;
      const int kc = (c >> 4) & 7;
      const int row = (c >> 7) * 16 + (c & 15);
      uint4 vb_;
      if (kc < 2) vb_ = *(const uint4*)(LBz + (n0 + row) * 16 + kc * 8);
      else { vb_.x = vb_.y = vb_.z = vb_.w = 0u; }
      *(uint4*)(&Bs[0][c * 8]) = vb_;
    }
    __syncthreads();
    short8 a2[4], b2[4];
#pragma unroll
    for (int i = 0; i < 4; ++i)
      a2[i] = *(const short8*)(&As[0][((wr * 4 + i) * 128 + lane) * 8]);
#pragma unroll
    for (int j = 0; j < 4; ++j)
      b2[j] = *(const short8*)(&Bs[0][((wc * 4 + j) * 128 + lane) * 8]);
#pragma unroll
    for (int i = 0; i < 4; ++i)
#pragma unroll
      for (int j = 0; j < 4; ++j)
        acc[i][j] = __builtin_amdgcn_mfma_f32_16x16x32_bf16(a2[i], b2[j], acc[i][j], 0, 0, 0);
  } else {
    // drain in-flight LDS-DMA before the block can retire
    asm volatile("s_waitcnt vmcnt(0)" ::: "memory");
  }

#pragma unroll
  for (int i = 0; i < 4; ++i) {
    const long row = m0 + wr * 64 + i * 16 + quad * 4;
#pragma unroll
    for (int j = 0; j < 4; ++j) {
      const long col = n0 + wc * 64 + j * 16 + l16;
#pragma unroll
      for (int rr = 0; rr < 4; ++rr) {
        float val = acc[i][j][rr] * scale;
        if constexpr (OUTF32)
          ((float*)Cv)[(long)blockIdx.z * batC + (row + rr) * ldc + col] = val;
        else
          ((unsigned short*)Cv)[(long)blockIdx.z * batC + (row + rr) * ldc + col] = f2bf(val);
      }
    }
  }
#undef STG_A
#undef STG_B
}

__device__ __forceinline__ uint4 pack8(const float* x) {
  float4 a = *(const float4*)x;
  float4 b = *(const float4*)(x + 4);
  uint4 o;
  o.x = (unsigned int)f2bf(a.x) | ((unsigned int)f2bf(a.y) << 16);
  o.y = (unsigned int)f2bf(a.z) | ((unsigned int)f2bf(a.w) << 16);
  o.z = (unsigned int)f2bf(b.x) | ((unsigned int)f2bf(b.y) << 16);
  o.w = (unsigned int)f2bf(b.z) | ((unsigned int)f2bf(b.w) << 16);
  return o;
}

// pure fp32->bf16 convert of q/k/v. grid (512, 3), 16384 elems/block.
__global__ __launch_bounds__(256) void prep_qkv(
    const float* __restrict__ q, const float* __restrict__ k, const float* __restrict__ v,
    unsigned short* __restrict__ qb, unsigned short* __restrict__ kb,
    unsigned short* __restrict__ vb) {
  const float* X; unsigned short* Y;
  if (blockIdx.y == 0)      { X = q; Y = qb; }
  else if (blockIdx.y == 1) { X = k; Y = kb; }
  else                      { X = v; Y = vb; }
  const int tid = threadIdx.x;
  const long blk = (long)blockIdx.x * 16384;
#pragma unroll
  for (int it = 0; it < 8; ++it) {
    const long idx = blk + it * 2048 + tid * 8;
    *(uint4*)(Y + idx) = pack8(X + idx);
  }
}

// all weight converts in one dispatch. grid (512, 5):
//  y<4: big 1024x1024 matrices (Wq,Wk,Wv,Wo), x in [0,512)
//  y==4: six 16k matrices (QB,KB,VB,QA,KA,VA), x in [0,48): mat=x>>3, sub=x&7
__global__ __launch_bounds__(256) void cvt_all(
    const float* __restrict__ Wq, const float* __restrict__ Wk,
    const float* __restrict__ Wv, const float* __restrict__ Wo,
    const float* __restrict__ QB, const float* __restrict__ KB, const float* __restrict__ VB,
    const float* __restrict__ QA, const float* __restrict__ KA, const float* __restrict__ VA,
    unsigned short* __restrict__ wqb, unsigned short* __restrict__ wkb,
    unsigned short* __restrict__ wvb, unsigned short* __restrict__ wob,
    unsigned short* __restrict__ Bqb, unsigned short* __restrict__ Bkb, unsigned short* __restrict__ Bvb,
    unsigned short* __restrict__ Aqb, unsigned short* __restrict__ Akb, unsigned short* __restrict__ Avb) {
  if (blockIdx.y < 4) {
    const float* x; unsigned short* y;
    switch (blockIdx.y) {
      case 0: x = Wq; y = wqb; break;
      case 1: x = Wk; y = wkb; break;
      case 2: x = Wv; y = wvb; break;
      default: x = Wo; y = wob; break;
    }
    const long i = ((long)blockIdx.x * 256 + threadIdx.x) * 8;
    *(uint4*)(y + i) = pack8(x + i);
  } else {
    if (blockIdx.x >= 48) return;
    const int mat = blockIdx.x >> 3, sub = blockIdx.x & 7;
    const float* x; unsigned short* y;
    switch (mat) {
      case 0: x = QB; y = Bqb; break;
      case 1: x = KB; y = Bkb; break;
      case 2: x = VB; y = Bvb; break;
      case 3: x = QA; y = Aqb; break;
      case 4: x = KA; y = Akb; break;
      default: x = VA; y = Avb; break;
    }
    const long i = ((long)sub * 256 + threadIdx.x) * 8;
    *(uint4*)(y + i) = pack8(x + i);
  }
}

// T[8192][16] = Xb @ Am^T via MFMA. grid (128, 3): 64 rows/block, 16/wave.
__global__ __launch_bounds__(256) void lora_t_mfma(
    const unsigned short* __restrict__ qb, const unsigned short* __restrict__ kb,
    const unsigned short* __restrict__ vb,
    const unsigned short* __restrict__ Aq, const unsigned short* __restrict__ Ak,
    const unsigned short* __restrict__ Av,
    unsigned short* __restrict__ Tq, unsigned short* __restrict__ Tk,
    unsigned short* __restrict__ Tv) {
  const unsigned short* X; const unsigned short* Am; unsigned short* T;
  if (blockIdx.y == 0)      { X = qb; Am = Aq; T = Tq; }
  else if (blockIdx.y == 1) { X = kb; Am = Ak; T = Tk; }
  else                      { X = vb; Am = Av; T = Tv; }
  const int tid = threadIdx.x, wave = tid >> 6, lane = tid & 63;
  const int quad = lane >> 4, l16 = lane & 15;
  const long m0 = (long)blockIdx.x * 64 + wave * 16;
  floatx4 acc = (floatx4){0.f, 0.f, 0.f, 0.f};
  const unsigned short* xp = X + (m0 + l16) * 1024 + quad * 8;
  const unsigned short* ap = Am + (long)l16 * 1024 + quad * 8;
#pragma unroll 4
  for (int k0 = 0; k0 < 1024; k0 += 32) {
    short8 af = *(const short8*)(xp + k0);
    short8 bf = *(const short8*)(ap + k0);
    acc = __builtin_amdgcn_mfma_f32_16x16x32_bf16(af, bf, acc, 0, 0, 0);
  }
#pragma unroll
  for (int rr = 0; rr < 4; ++rr)
    T[(m0 + quad * 4 + rr) * 16 + l16] = f2bf(acc[rr]);
}

// in-place row softmax over 2048 bf16 scores; one block per row
__global__ __launch_bounds__(256) void softmax_kernel(unsigned short* __restrict__ S) {
  const long base = (long)blockIdx.x * 2048;
  const int tid = threadIdx.x;
  const int lane = tid & 63, wave = tid >> 6;
  __shared__ float redm[4], reds[4];
  uint4 raw = *(const uint4*)(S + base + tid * 8);
  unsigned int w[4] = {raw.x, raw.y, raw.z, raw.w};
  float v[8];
#pragma unroll
  for (int i = 0; i < 4; ++i) {
    v[2 * i]     = bf2f((unsigned short)(w[i] & 0xffffu));
    v[2 * i + 1] = bf2f((unsigned short)(w[i] >> 16));
  }
  float m = v[0];
#pragma unroll
  for (int i = 1; i < 8; ++i) m = fmaxf(m, v[i]);
  for (int off = 32; off >= 1; off >>= 1) m = fmaxf(m, __shfl_xor(m, off, 64));
  if (lane == 0) redm[wave] = m;
  __syncthreads();
  m = fmaxf(fmaxf(redm[0], redm[1]), fmaxf(redm[2], redm[3]));
  float e[8], s = 0.f;
#pragma unroll
  for (int i = 0; i < 8; ++i) { e[i] = __expf(v[i] - m); s += e[i]; }
  for (int off = 32; off >= 1; off >>= 1) s += __shfl_xor(s, off, 64);
  if (lane == 0) reds[wave] = s;
  __syncthreads();
  s = reds[0] + reds[1] + reds[2] + reds[3];
  const float inv = 1.0f / s;
  uint4 o;
  o.x = (unsigned int)f2bf(e[0] * inv) | ((unsigned int)f2bf(e[1] * inv) << 16);
  o.y = (unsigned int)f2bf(e[2] * inv) | ((unsigned int)f2bf(e[3] * inv) << 16);
  o.z = (unsigned int)f2bf(e[4] * inv) | ((unsigned int)f2bf(e[5] * inv) << 16);
  o.w = (unsigned int)f2bf(e[6] * inv) | ((unsigned int)f2bf(e[7] * inv) << 16);
  *(uint4*)(S + base + tid * 8) = o;
}

extern "C" void kernel_launch(void* const* d_in, const int* in_sizes, int n_in,
                              void* d_out, int out_size, void* d_ws, size_t ws_size,
                              hipStream_t stream) {
  const float* q  = (const float*)d_in[0];
  const float* k  = (const float*)d_in[1];
  const float* v  = (const float*)d_in[2];
  const float* Wq = (const float*)d_in[3];
  const float* Wk = (const float*)d_in[4];
  const float* Wv = (const float*)d_in[5];
  const float* QA = (const float*)d_in[6];
  const float* QB = (const float*)d_in[7];
  const float* KA = (const float*)d_in[8];
  const float* KB = (const float*)d_in[9];
  const float* VA = (const float*)d_in[10];
  const float* VB = (const float*)d_in[11];
  const float* Wo = (const float*)d_in[12];

  unsigned short* W = (unsigned short*)d_ws;
  const long SEe = (long)8192 * 1024;  // 8388608
  unsigned short* qb  = W;             // dead after Q-proj -> scores low half
  unsigned short* kb  = W + SEe;
  unsigned short* vb  = W + 2 * SEe;   // dead after V-proj -> attn buffer
  unsigned short* Qp  = W + 3 * SEe;
  unsigned short* Kp  = W + 4 * SEe;
  unsigned short* VT  = W + 5 * SEe;   // [1024][8192] = V^T
  unsigned short* wqb = W + 6 * SEe;
  unsigned short* wkb = wqb + 1048576;
  unsigned short* wvb = wkb + 1048576;
  unsigned short* wob = wvb + 1048576;
  unsigned short* Bqb = wob + 1048576;
  unsigned short* Bkb = Bqb + 16384;
  unsigned short* Bvb = Bkb + 16384;
  unsigned short* Aqb = Bvb + 16384;
  unsigned short* Akb = Aqb + 16384;
  unsigned short* Avb = Akb + 16384;
  unsigned short* Tq  = Avb + 16384;   // [8192][16]
  unsigned short* Tk  = Tq + 131072;
  unsigned short* Tv  = Tk + 131072;
  unsigned short* scores = W;          // [4][2048][2048] bf16, aliases qb+kb
  unsigned short* attn   = vb;         // [8192][1024] bf16, aliases vb

  dim3 blk(256, 1, 1), blk5(512, 1, 1);
  prep_qkv<<<dim3(512, 3, 1), blk, 0, stream>>>(q, k, v, qb, kb, vb);
  cvt_all<<<dim3(512, 5, 1), blk, 0, stream>>>(Wq, Wk, Wv, Wo, QB, KB, VB, QA, KA, VA,
                                               wqb, wkb, wvb, wob, Bqb, Bkb, Bvb, Aqb, Akb, Avb);
  lora_t_mfma<<<dim3(128, 3, 1), blk, 0, stream>>>(qb, kb, vb, Aqb, Akb, Avb, Tq, Tk, Tv);

  // Q = qb@Wq^T + Tq@Bq^T ; K likewise (z batches; M=8192,N=1024,K=1024)
  gemm3b<true, false, true><<<dim3(8, 32, 2), blk5, 0, stream>>>(
      qb, wqb, Qp, Tq, Bqb, 1024, 1024, 1024, 1024, 1.0f,
      SEe, 1048576, SEe, 131072, 16384);
  // VT = Wv@vb^T + Bv@Tv^T  (M=1024,N=8192): OWNN -> 256 wg
  gemm3b<true, false, false><<<dim3(64, 4, 1), blk5, 0, stream>>>(
      wvb, vb, VT, Bvb, Tv, 1024, 1024, 8192, 1024, 1.0f, 0, 0, 0, 0, 0);
  // scores = Qp@Kp^T / 32   (batched, M=N=2048,K=1024) -> 512 wg
  gemm3b<false, false, true><<<dim3(16, 8, 4), blk5, 0, stream>>>(
      Qp, Kp, scores, nullptr, nullptr, 1024, 1024, 2048, 1024, 0.03125f,
      (long)S_LEN * E_DIM, (long)S_LEN * E_DIM, (long)S_LEN * S_LEN, 0, 0);
  softmax_kernel<<<8192, blk, 0, stream>>>(scores);
  // attn_out = P@V = P@(VT)^T  (batched, M=2048,N=1024,K=2048) -> 256 wg
  gemm3b<false, false, true><<<dim3(8, 8, 4), blk5, 0, stream>>>(
      scores, VT, attn, nullptr, nullptr, 2048, 8192, 1024, 2048, 1.0f,
      (long)S_LEN * S_LEN, (long)S_LEN, (long)S_LEN * E_DIM, 0, 0);
  // final = attn@Wo^T -> fp32 d_out  (M=8192,N=1024,K=1024) -> 256 wg
  gemm3b<false, true, true><<<dim3(8, 32, 1), blk5, 0, stream>>>(
      attn, wob, d_out, nullptr, nullptr, 1024, 1024, 1024, 1024, 1.0f, 0, 0, 0, 0, 0);
}

// Round 5
// 414.580 us; speedup vs baseline: 1.1122x; 1.0272x over previous
//
#include <hip/hip_runtime.h>

// LoRA attention: B=4, S=2048, E=1024, R=16, fp32 in/out.
// R10 changes vs R9 (425.9us):
//  - R9's hot gemm (Q/K proj, 66.5us) ran with Occupancy 19.7% = ONE 8-wave
//    block/CU (144KB LDS). Per-tile: ~2200cyc of pipe work vs ~5000cyc
//    measured -> 55% stall, unfillable with a single resident block (every
//    entry-wait idles the whole CU).
//  - BK 64 -> 32: LDS = 3 bufs x (256x32 A + 128x32 B) x 2B = 72KB
//    -> TWO blocks/CU. Same counted-vmcnt 3-buffer pipeline (entry
//    vmcnt(3), never 0 in loop), same fragment-major layout, same grids;
//    co-resident block fills the entry-wait stalls (R5's TLP + R9's
//    schedule, combined).
//  - __launch_bounds__(512,4): 2 blocks x 8 waves / 4 SIMD = 4 waves/EU,
//    VGPR cap 128 (structure needs ~80; R9 measured 88 w/ 2x fragments).
// Race-freedom per tile t (cur = t%3):
//  - entry: vmcnt(3)+lgkmcnt(0)+barrier => tile t's 3 loads (issued at t-2)
//    landed; t+1's 3 in flight; all waves' reads of buf[(t-1)%3] drained.
//  - stage tile t+2 into buf[(t+2)%3] == buf[(t-1)%3] (just freed).
//  - clamped dummy stages on the last 2 tiles keep vmcnt uniform; they
//    target buffers never read again.

#define S_LEN 2048
#define E_DIM 1024

typedef __attribute__((ext_vector_type(8))) short short8;
typedef __attribute__((ext_vector_type(4))) float floatx4;

__device__ __forceinline__ unsigned short f2bf(float f) {
  union { float f; unsigned int u; } x; x.f = f;
  return (unsigned short)((x.u + 0x7fffu + ((x.u >> 16) & 1u)) >> 16);  // RNE
}
__device__ __forceinline__ float bf2f(unsigned short h) {
  union { unsigned int u; float f; } x; x.u = ((unsigned int)h) << 16;
  return x.f;
}

__device__ __forceinline__ void gld_lds16(const unsigned short* g, unsigned short* l) {
  __builtin_amdgcn_global_load_lds(
      (const __attribute__((address_space(1))) unsigned int*)(const void*)g,
      (__attribute__((address_space(3))) unsigned int*)(void*)l,
      16, 0, 0);
}

// C[m][n] = scale * (sum_k A[m][k]*B[n][k]  (+ LoRA: sum_r LA[m][r]*LB[n][r]))
// BM=256 x BN=128, BK=32, 512 threads (8 waves, 4M x 2N), 64x64 out per wave.
// LDS fragment-major per 64-row group: 16B chunk (row,kc), kc in [0,4), at
// chunk index (row>>4)*64 + kc*16 + (row&15) within its group; fragment
// (16-row group g) = ds_read_b128 at chunk g*64 + lane (lane-contiguous,
// 0 bank conflicts). gld_lds dest linear (chunk == L*512 + tid), source
// pre-swizzled: row = ((c>>6)<<4)|(c&15), koff = ((c>>4)&3)*8.
template<bool LORA, bool OUTF32, bool OWNM>
__global__ __launch_bounds__(512, 4) void gemm3b(
    const unsigned short* __restrict__ A, const unsigned short* __restrict__ B,
    void* __restrict__ Cv,
    const unsigned short* __restrict__ LA, const unsigned short* __restrict__ LB,
    long lda, long ldb, long ldc, int K, float scale,
    long batA, long batB, long batC, long batLA, long batLB) {
  __shared__ alignas(16) unsigned short As[3][8192];  // 3 bufs x (256 x 32)
  __shared__ alignas(16) unsigned short Bs[3][4096];  // 3 bufs x (128 x 32)

  const int tid  = threadIdx.x;
  const int wave = tid >> 6, lane = tid & 63;
  const int quad = lane >> 4, l16 = lane & 15;
  const int wr = wave >> 1, wc = wave & 1;  // 4x2 waves, each 64x64

  // XCD-aware swizzle: xcd = flat%8 owns a chunk of the M (or N) tiles and
  // sweeps the other dimension fastest. Per-z wg counts are multiples of 8.
  const int Nx = (int)gridDim.x, Ny = (int)gridDim.y;
  const int wg2 = (int)blockIdx.x + Nx * (int)blockIdx.y;
  const int xcd = wg2 & 7, ii = wg2 >> 3;
  int bx, by;
  if constexpr (OWNM) {
    const int lg = 31 - __clz(Nx);
    by = xcd * (Ny >> 3) + (ii >> lg);
    bx = ii & (Nx - 1);
  } else {
    const int lg = 31 - __clz(Ny);
    bx = xcd * (Nx >> 3) + (ii >> lg);
    by = ii & (Ny - 1);
  }
  const long m0 = (long)by * 256;
  const long n0 = (long)bx * 128;
  const unsigned short* Az = A + (long)blockIdx.z * batA;
  const unsigned short* Bz = B + (long)blockIdx.z * batB;

  floatx4 acc[4][4];
#pragma unroll
  for (int i = 0; i < 4; ++i)
#pragma unroll
    for (int j = 0; j < 4; ++j) acc[i][j] = (floatx4){0.f, 0.f, 0.f, 0.f};

  // Stage source mapping for chunk c = L*512 + tid:
  // row = ((c>>6)<<4)|(c&15) (L=1 -> +128 rows), koff = ((c>>4)&3)*8.
  const int c0r = ((tid >> 6) << 4) | (tid & 15);
  const int c0k = ((tid >> 4) & 3) << 3;
  const unsigned short* a0 = Az + (m0 + c0r) * lda + c0k;
  const unsigned short* b0 = Bz + (n0 + c0r) * ldb + c0k;

#define STG_A(bf, k0)                                                   \
  do {                                                                  \
    gld_lds16(a0 + (k0), &As[bf][tid * 8]);                             \
    gld_lds16(a0 + 128 * lda + (k0), &As[bf][4096 + tid * 8]);          \
  } while (0)
#define STG_B(bf, k0)                                                   \
  do {                                                                  \
    gld_lds16(b0 + (k0), &Bs[bf][tid * 8]);                             \
  } while (0)

  // prologue: tile 0 -> buf0, tile 1 -> buf1 (6 loads total).
  STG_A(0, 0); STG_B(0, 0);
  STG_A(1, 32); STG_B(1, 32);

  const int NT = K >> 5;
  int cur = 0;
  for (int t = 0; t < NT; ++t) {
    const int s2 = (cur == 0) ? 2 : cur - 1;  // (cur+2)%3
    const int kA = (t + 2 < NT ? t + 2 : NT - 1) << 5;
    const unsigned short* ra = &As[cur][0];
    const unsigned short* rb = &Bs[cur][0];

    // entry: per-wave drain of our prev-tile ds_reads, wait tile t's 3 loads
    // (issued during t-2; t+1's 3 remain in flight), then sync.
    asm volatile("s_waitcnt vmcnt(3) lgkmcnt(0)\n\ts_barrier" ::: "memory");

    short8 af[4], bf_[4];
#pragma unroll
    for (int i = 0; i < 4; ++i)
      af[i] = *(const short8*)(ra + ((wr * 4 + i) * 64 + lane) * 8);
#pragma unroll
    for (int j = 0; j < 4; ++j)
      bf_[j] = *(const short8*)(rb + ((wc * 4 + j) * 64 + lane) * 8);
    // stage tile t+2 into buf s2 (== buf[(t-1)%3], freed by this entry)
    STG_A(s2, kA);
    STG_B(s2, kA);

    __builtin_amdgcn_s_setprio(1);
#pragma unroll
    for (int i = 0; i < 4; ++i)
#pragma unroll
      for (int j = 0; j < 4; ++j)
        acc[i][j] = __builtin_amdgcn_mfma_f32_16x16x32_bf16(
            af[i], bf_[j], acc[i][j], 0, 0, 0);
    __builtin_amdgcn_s_setprio(0);

    cur = (cur == 2) ? 0 : cur + 1;
  }

  if constexpr (LORA) {
    // drain all in-flight LDS-DMA (incl. dummies), then sync all waves
    asm volatile("s_waitcnt vmcnt(0)" ::: "memory");
    __syncthreads();
    const unsigned short* LAz = LA + (long)blockIdx.z * batLA;
    const unsigned short* LBz = LB + (long)blockIdx.z * batLB;
    // Fill buf0 with LoRA operands in the same fragment-major layout:
    // kc 0..1 = ranks 0..15, kc 2..3 zero (one MFMA covers k 0..31).
#pragma unroll
    for (int cc = 0; cc < 2; ++cc) {  // A: 1024 chunks
      const int c = cc * 512 + tid;
      const int kc = (c >> 4) & 3;
      const int row = ((c >> 6) << 4) | (c & 15);
      uint4 va;
      if (kc < 2) va = *(const uint4*)(LAz + (m0 + row) * 16 + kc * 8);
      else { va.x = va.y = va.z = va.w = 0u; }
      *(uint4*)(&As[0][c * 8]) = va;
    }
    {  // B: 512 chunks
      const int c = tid;
      const int kc = (c >> 4) & 3;
      const int row = ((c >> 6) << 4) | (c & 15);
      uint4 vb_;
      if (kc < 2) vb_ = *(const uint4*)(LBz + (n0 + row) * 16 + kc * 8);
      else { vb_.x = vb_.y = vb_.z = vb_.w = 0u; }
      *(uint4*)(&Bs[0][c * 8]) = vb_;
    }
    __syncthreads();
    short8 a2[4], b2[4];
#pragma unroll
    for (int i = 0; i < 4; ++i)
      a2[i] = *(const short8*)(&As[0][((wr * 4 + i) * 64 + lane) * 8]);
#pragma unroll
    for (int j = 0; j < 4; ++j)
      b2[j] = *(const short8*)(&Bs[0][((wc * 4 + j) * 64 + lane) * 8]);
#pragma unroll
    for (int i = 0; i < 4; ++i)
#pragma unroll
      for (int j = 0; j < 4; ++j)
        acc[i][j] = __builtin_amdgcn_mfma_f32_16x16x32_bf16(a2[i], b2[j], acc[i][j], 0, 0, 0);
  } else {
    // drain in-flight LDS-DMA before the block can retire
    asm volatile("s_waitcnt vmcnt(0)" ::: "memory");
  }

#pragma unroll
  for (int i = 0; i < 4; ++i) {
    const long row = m0 + wr * 64 + i * 16 + quad * 4;
#pragma unroll
    for (int j = 0; j < 4; ++j) {
      const long col = n0 + wc * 64 + j * 16 + l16;
#pragma unroll
      for (int rr = 0; rr < 4; ++rr) {
        float val = acc[i][j][rr] * scale;
        if constexpr (OUTF32)
          ((float*)Cv)[(long)blockIdx.z * batC + (row + rr) * ldc + col] = val;
        else
          ((unsigned short*)Cv)[(long)blockIdx.z * batC + (row + rr) * ldc + col] = f2bf(val);
      }
    }
  }
#undef STG_A
#undef STG_B
}

__device__ __forceinline__ uint4 pack8(const float* x) {
  float4 a = *(const float4*)x;
  float4 b = *(const float4*)(x + 4);
  uint4 o;
  o.x = (unsigned int)f2bf(a.x) | ((unsigned int)f2bf(a.y) << 16);
  o.y = (unsigned int)f2bf(a.z) | ((unsigned int)f2bf(a.w) << 16);
  o.z = (unsigned int)f2bf(b.x) | ((unsigned int)f2bf(b.y) << 16);
  o.w = (unsigned int)f2bf(b.z) | ((unsigned int)f2bf(b.w) << 16);
  return o;
}

// pure fp32->bf16 convert of q/k/v. grid (512, 3), 16384 elems/block.
__global__ __launch_bounds__(256) void prep_qkv(
    const float* __restrict__ q, const float* __restrict__ k, const float* __restrict__ v,
    unsigned short* __restrict__ qb, unsigned short* __restrict__ kb,
    unsigned short* __restrict__ vb) {
  const float* X; unsigned short* Y;
  if (blockIdx.y == 0)      { X = q; Y = qb; }
  else if (blockIdx.y == 1) { X = k; Y = kb; }
  else                      { X = v; Y = vb; }
  const int tid = threadIdx.x;
  const long blk = (long)blockIdx.x * 16384;
#pragma unroll
  for (int it = 0; it < 8; ++it) {
    const long idx = blk + it * 2048 + tid * 8;
    *(uint4*)(Y + idx) = pack8(X + idx);
  }
}

// all weight converts in one dispatch. grid (512, 5):
//  y<4: big 1024x1024 matrices (Wq,Wk,Wv,Wo), x in [0,512)
//  y==4: six 16k matrices (QB,KB,VB,QA,KA,VA), x in [0,48): mat=x>>3, sub=x&7
__global__ __launch_bounds__(256) void cvt_all(
    const float* __restrict__ Wq, const float* __restrict__ Wk,
    const float* __restrict__ Wv, const float* __restrict__ Wo,
    const float* __restrict__ QB, const float* __restrict__ KB, const float* __restrict__ VB,
    const float* __restrict__ QA, const float* __restrict__ KA, const float* __restrict__ VA,
    unsigned short* __restrict__ wqb, unsigned short* __restrict__ wkb,
    unsigned short* __restrict__ wvb, unsigned short* __restrict__ wob,
    unsigned short* __restrict__ Bqb, unsigned short* __restrict__ Bkb, unsigned short* __restrict__ Bvb,
    unsigned short* __restrict__ Aqb, unsigned short* __restrict__ Akb, unsigned short* __restrict__ Avb) {
  if (blockIdx.y < 4) {
    const float* x; unsigned short* y;
    switch (blockIdx.y) {
      case 0: x = Wq; y = wqb; break;
      case 1: x = Wk; y = wkb; break;
      case 2: x = Wv; y = wvb; break;
      default: x = Wo; y = wob; break;
    }
    const long i = ((long)blockIdx.x * 256 + threadIdx.x) * 8;
    *(uint4*)(y + i) = pack8(x + i);
  } else {
    if (blockIdx.x >= 48) return;
    const int mat = blockIdx.x >> 3, sub = blockIdx.x & 7;
    const float* x; unsigned short* y;
    switch (mat) {
      case 0: x = QB; y = Bqb; break;
      case 1: x = KB; y = Bkb; break;
      case 2: x = VB; y = Bvb; break;
      case 3: x = QA; y = Aqb; break;
      case 4: x = KA; y = Akb; break;
      default: x = VA; y = Avb; break;
    }
    const long i = ((long)sub * 256 + threadIdx.x) * 8;
    *(uint4*)(y + i) = pack8(x + i);
  }
}

// T[8192][16] = Xb @ Am^T via MFMA. grid (128, 3): 64 rows/block, 16/wave.
__global__ __launch_bounds__(256) void lora_t_mfma(
    const unsigned short* __restrict__ qb, const unsigned short* __restrict__ kb,
    const unsigned short* __restrict__ vb,
    const unsigned short* __restrict__ Aq, const unsigned short* __restrict__ Ak,
    const unsigned short* __restrict__ Av,
    unsigned short* __restrict__ Tq, unsigned short* __restrict__ Tk,
    unsigned short* __restrict__ Tv) {
  const unsigned short* X; const unsigned short* Am; unsigned short* T;
  if (blockIdx.y == 0)      { X = qb; Am = Aq; T = Tq; }
  else if (blockIdx.y == 1) { X = kb; Am = Ak; T = Tk; }
  else                      { X = vb; Am = Av; T = Tv; }
  const int tid = threadIdx.x, wave = tid >> 6, lane = tid & 63;
  const int quad = lane >> 4, l16 = lane & 15;
  const long m0 = (long)blockIdx.x * 64 + wave * 16;
  floatx4 acc = (floatx4){0.f, 0.f, 0.f, 0.f};
  const unsigned short* xp = X + (m0 + l16) * 1024 + quad * 8;
  const unsigned short* ap = Am + (long)l16 * 1024 + quad * 8;
#pragma unroll 4
  for (int k0 = 0; k0 < 1024; k0 += 32) {
    short8 af = *(const short8*)(xp + k0);
    short8 bf = *(const short8*)(ap + k0);
    acc = __builtin_amdgcn_mfma_f32_16x16x32_bf16(af, bf, acc, 0, 0, 0);
  }
#pragma unroll
  for (int rr = 0; rr < 4; ++rr)
    T[(m0 + quad * 4 + rr) * 16 + l16] = f2bf(acc[rr]);
}

// in-place row softmax over 2048 bf16 scores; one block per row
__global__ __launch_bounds__(256) void softmax_kernel(unsigned short* __restrict__ S) {
  const long base = (long)blockIdx.x * 2048;
  const int tid = threadIdx.x;
  const int lane = tid & 63, wave = tid >> 6;
  __shared__ float redm[4], reds[4];
  uint4 raw = *(const uint4*)(S + base + tid * 8);
  unsigned int w[4] = {raw.x, raw.y, raw.z, raw.w};
  float v[8];
#pragma unroll
  for (int i = 0; i < 4; ++i) {
    v[2 * i]     = bf2f((unsigned short)(w[i] & 0xffffu));
    v[2 * i + 1] = bf2f((unsigned short)(w[i] >> 16));
  }
  float m = v[0];
#pragma unroll
  for (int i = 1; i < 8; ++i) m = fmaxf(m, v[i]);
  for (int off = 32; off >= 1; off >>= 1) m = fmaxf(m, __shfl_xor(m, off, 64));
  if (lane == 0) redm[wave] = m;
  __syncthreads();
  m = fmaxf(fmaxf(redm[0], redm[1]), fmaxf(redm[2], redm[3]));
  float e[8], s = 0.f;
#pragma unroll
  for (int i = 0; i < 8; ++i) { e[i] = __expf(v[i] - m); s += e[i]; }
  for (int off = 32; off >= 1; off >>= 1) s += __shfl_xor(s, off, 64);
  if (lane == 0) reds[wave] = s;
  __syncthreads();
  s = reds[0] + reds[1] + reds[2] + reds[3];
  const float inv = 1.0f / s;
  uint4 o;
  o.x = (unsigned int)f2bf(e[0] * inv) | ((unsigned int)f2bf(e[1] * inv) << 16);
  o.y = (unsigned int)f2bf(e[2] * inv) | ((unsigned int)f2bf(e[3] * inv) << 16);
  o.z = (unsigned int)f2bf(e[4] * inv) | ((unsigned int)f2bf(e[5] * inv) << 16);
  o.w = (unsigned int)f2bf(e[6] * inv) | ((unsigned int)f2bf(e[7] * inv) << 16);
  *(uint4*)(S + base + tid * 8) = o;
}

extern "C" void kernel_launch(void* const* d_in, const int* in_sizes, int n_in,
                              void* d_out, int out_size, void* d_ws, size_t ws_size,
                              hipStream_t stream) {
  const float* q  = (const float*)d_in[0];
  const float* k  = (const float*)d_in[1];
  const float* v  = (const float*)d_in[2];
  const float* Wq = (const float*)d_in[3];
  const float* Wk = (const float*)d_in[4];
  const float* Wv = (const float*)d_in[5];
  const float* QA = (const float*)d_in[6];
  const float* QB = (const float*)d_in[7];
  const float* KA = (const float*)d_in[8];
  const float* KB = (const float*)d_in[9];
  const float* VA = (const float*)d_in[10];
  const float* VB = (const float*)d_in[11];
  const float* Wo = (const float*)d_in[12];

  unsigned short* W = (unsigned short*)d_ws;
  const long SEe = (long)8192 * 1024;  // 8388608
  unsigned short* qb  = W;             // dead after Q-proj -> scores low half
  unsigned short* kb  = W + SEe;
  unsigned short* vb  = W + 2 * SEe;   // dead after V-proj -> attn buffer
  unsigned short* Qp  = W + 3 * SEe;
  unsigned short* Kp  = W + 4 * SEe;
  unsigned short* VT  = W + 5 * SEe;   // [1024][8192] = V^T
  unsigned short* wqb = W + 6 * SEe;
  unsigned short* wkb = wqb + 1048576;
  unsigned short* wvb = wkb + 1048576;
  unsigned short* wob = wvb + 1048576;
  unsigned short* Bqb = wob + 1048576;
  unsigned short* Bkb = Bqb + 16384;
  unsigned short* Bvb = Bkb + 16384;
  unsigned short* Aqb = Bvb + 16384;
  unsigned short* Akb = Aqb + 16384;
  unsigned short* Avb = Akb + 16384;
  unsigned short* Tq  = Avb + 16384;   // [8192][16]
  unsigned short* Tk  = Tq + 131072;
  unsigned short* Tv  = Tk + 131072;
  unsigned short* scores = W;          // [4][2048][2048] bf16, aliases qb+kb
  unsigned short* attn   = vb;         // [8192][1024] bf16, aliases vb

  dim3 blk(256, 1, 1), blk5(512, 1, 1);
  prep_qkv<<<dim3(512, 3, 1), blk, 0, stream>>>(q, k, v, qb, kb, vb);
  cvt_all<<<dim3(512, 5, 1), blk, 0, stream>>>(Wq, Wk, Wv, Wo, QB, KB, VB, QA, KA, VA,
                                               wqb, wkb, wvb, wob, Bqb, Bkb, Bvb, Aqb, Akb, Avb);
  lora_t_mfma<<<dim3(128, 3, 1), blk, 0, stream>>>(qb, kb, vb, Aqb, Akb, Avb, Tq, Tk, Tv);

  // Q = qb@Wq^T + Tq@Bq^T ; K likewise (z batches; M=8192,N=1024,K=1024)
  gemm3b<true, false, true><<<dim3(8, 32, 2), blk5, 0, stream>>>(
      qb, wqb, Qp, Tq, Bqb, 1024, 1024, 1024, 1024, 1.0f,
      SEe, 1048576, SEe, 131072, 16384);
  // VT = Wv@vb^T + Bv@Tv^T  (M=1024,N=8192): OWNN -> 256 wg
  gemm3b<true, false, false><<<dim3(64, 4, 1), blk5, 0, stream>>>(
      wvb, vb, VT, Bvb, Tv, 1024, 1024, 8192, 1024, 1.0f, 0, 0, 0, 0, 0);
  // scores = Qp@Kp^T / 32   (batched, M=N=2048,K=1024) -> 512 wg
  gemm3b<false, false, true><<<dim3(16, 8, 4), blk5, 0, stream>>>(
      Qp, Kp, scores, nullptr, nullptr, 1024, 1024, 2048, 1024, 0.03125f,
      (long)S_LEN * E_DIM, (long)S_LEN * E_DIM, (long)S_LEN * S_LEN, 0, 0);
  softmax_kernel<<<8192, blk, 0, stream>>>(scores);
  // attn_out = P@V = P@(VT)^T  (batched, M=2048,N=1024,K=2048) -> 256 wg
  gemm3b<false, false, true><<<dim3(8, 8, 4), blk5, 0, stream>>>(
      scores, VT, attn, nullptr, nullptr, 2048, 8192, 1024, 2048, 1.0f,
      (long)S_LEN * S_LEN, (long)S_LEN, (long)S_LEN * E_DIM, 0, 0);
  // final = attn@Wo^T -> fp32 d_out  (M=8192,N=1024,K=1024) -> 256 wg
  gemm3b<false, true, true><<<dim3(8, 32, 1), blk5, 0, stream>>>(
      attn, wob, d_out, nullptr, nullptr, 1024, 1024, 1024, 1024, 1.0f, 0, 0, 0, 0, 0);
}

// Round 6
// 380.349 us; speedup vs baseline: 1.2123x; 1.0900x over previous
//
#include <hip/hip_runtime.h>

// LoRA attention: B=4, S=2048, E=1024, R=16, fp32 in/out.
// R11: faithful m201-class 8-phase port (R9/R10 plateaued at ~2.1 TF/CU =
// the documented 2-phase-family ceiling; nothing saturated in counters).
//  - 256^2 tile, BK=64, 8 waves (2Mx4N, 128x64/wave), 128KB LDS
//    (2 buf x {A,B} x 2 halves). Halves split by FRAGMENT GROUP (A-F0 =
//    rows {0-63,128-191} = frag i0-3 for both wr; B-G0 = {0-31,64-95,
//    128-159,192-223} = frag j0-1 for all wc) so each phase depends on
//    exactly one staged half.
//  - 4 phases/K-tile: ph0 A-F0xB-G0, ph1 A-F1xB-G0, ph2 A-F0xB-G1,
//    ph3 A-F1xB-G1. Per phase: vmcnt(4)+barrier -> ds_reads -> stage one
//    half of tile t+1 -> lgkmcnt(0) -> setprio(1) -> 16 MFMA -> setprio(0).
//    Waited half was staged 3-4 phases earlier; queue never < 4 loads.
//  - LDS row-major + XOR swizzle (byte ^= (row&7)<<4), BOTH sides:
//    inverse-permuted global source (within each 128B row -> coalescing
//    preserved: 8x128B full lines per wave vs prior scatter's 16x64B) +
//    swizzled ds_read addr (per-quarter-wave 2-way = free).
//  - LoRA epilogue via direct per-lane global loads (R=16; no LDS refill).
// vmcnt(4) proof (in-order retirement): at ph-p wait, queue (old->new) =
// [needed half, <=2 newer halves]; vmcnt(4) retires everything older than
// the newest 4 loads => needed half landed. Prologue stages tile0's 4
// halves in consumption order AF0,BG0,AF1,BG1.

#define S_LEN 2048
#define E_DIM 1024

typedef __attribute__((ext_vector_type(8))) short short8;
typedef __attribute__((ext_vector_type(4))) float floatx4;

__device__ __forceinline__ unsigned short f2bf(float f) {
  union { float f; unsigned int u; } x; x.f = f;
  return (unsigned short)((x.u + 0x7fffu + ((x.u >> 16) & 1u)) >> 16);  // RNE
}
__device__ __forceinline__ float bf2f(unsigned short h) {
  union { unsigned int u; float f; } x; x.u = ((unsigned int)h) << 16;
  return x.f;
}

__device__ __forceinline__ void gld_lds16(const unsigned short* g, unsigned short* l) {
  __builtin_amdgcn_global_load_lds(
      (const __attribute__((address_space(1))) unsigned int*)(const void*)g,
      (__attribute__((address_space(3))) unsigned int*)(void*)l,
      16, 0, 0);
}

// C[m][n] = scale * (sum_k A[m][k]*B[n][k]  (+ LoRA: sum_r LA[m][r]*LB[n][r]))
template<bool LORA, bool OUTF32, bool OWNM>
__global__ __launch_bounds__(512, 2) void gemm8p(
    const unsigned short* __restrict__ A, const unsigned short* __restrict__ B,
    void* __restrict__ Cv,
    const unsigned short* __restrict__ LA, const unsigned short* __restrict__ LB,
    long lda, long ldb, long ldc, int K, float scale,
    long batA, long batB, long batC, long batLA, long batLB) {
  // [buf][half][128 rows x 64 bf16 (128B, XOR-swizzled)]
  __shared__ alignas(16) unsigned short As[2][2][8192];
  __shared__ alignas(16) unsigned short Bs[2][2][8192];

  const int tid  = threadIdx.x;
  const int wave = tid >> 6, lane = tid & 63;
  const int quad = lane >> 4, l16 = lane & 15;
  const int wr = wave >> 2, wc = wave & 3;  // 2M x 4N waves, each 128x64

  // XCD-aware swizzle (per-z wg counts are multiples of 8; dims pow2).
  const int Nx = (int)gridDim.x, Ny = (int)gridDim.y;
  const int wg2 = (int)blockIdx.x + Nx * (int)blockIdx.y;
  const int xcd = wg2 & 7, ii = wg2 >> 3;
  int bx, by;
  if constexpr (OWNM) {
    const int lg = 31 - __clz(Nx);
    by = xcd * (Ny >> 3) + (ii >> lg);
    bx = ii & (Nx - 1);
  } else {
    const int lg = 31 - __clz(Ny);
    bx = xcd * (Nx >> 3) + (ii >> lg);
    by = ii & (Ny - 1);
  }
  const long m0 = (long)by * 256;
  const long n0 = (long)bx * 256;
  const unsigned short* Az = A + (long)blockIdx.z * batA;
  const unsigned short* Bz = B + (long)blockIdx.z * batB;

  floatx4 acc[8][4];
#pragma unroll
  for (int i = 0; i < 8; ++i)
#pragma unroll
    for (int j = 0; j < 4; ++j) acc[i][j] = (floatx4){0.f, 0.f, 0.f, 0.f};

  // ---- staging addresses (thread stages chunks c=tid and c=tid+512 of a
  // 128-row x 128B half; lr = c>>3 local row, slot permuted by row&7).
  const int lr = tid >> 3;                 // 0..63 (chunk2: +64)
  const int sp = (tid & 7) ^ (lr & 7);     // inverse-swizzled source slot
  // A half F: local rows lr<64 -> global m0 + lr + F*64; lr>=64 -> +128.
  const unsigned short* aS = Az + (m0 + lr) * lda + sp * 8;
  // B half G: global n-row = (lr>>5)*64 + (lr&31) + G*32 (chunk2: +128).
  const unsigned short* bS = Bz + (n0 + (lr >> 5) * 64 + (lr & 31)) * ldb + sp * 8;

#define STG_A(bf, F, k0)                                                     \
  do {                                                                       \
    gld_lds16(aS + (long)((F) * 64) * lda + (k0), &As[bf][F][tid * 8]);      \
    gld_lds16(aS + (long)((F) * 64 + 128) * lda + (k0),                      \
              &As[bf][F][4096 + tid * 8]);                                   \
  } while (0)
#define STG_B(bf, G, k0)                                                     \
  do {                                                                       \
    gld_lds16(bS + (long)((G) * 32) * ldb + (k0), &Bs[bf][G][tid * 8]);      \
    gld_lds16(bS + (long)((G) * 32 + 128) * ldb + (k0),                      \
              &Bs[bf][G][4096 + tid * 8]);                                   \
  } while (0)

  // ---- fragment-read constants (ushort indices). Read byte =
  // lrow*128 + ((ks*64 + quad*16) ^ ((lrow&7)<<4)); lrow&7 == l16&7.
  const int xo    = (l16 & 7) << 4;
  const int aoff0 = ((quad * 16) ^ xo) >> 1;
  const int aoff1 = ((64 + quad * 16) ^ xo) >> 1;
  const int arow  = wr * 4096 + l16 * 64;  // + (i&3)*1024
  const int brow  = wc * 2048 + l16 * 64;  // + (j&1)*1024

  // prologue: tile 0's halves in consumption order.
  STG_A(0, 0, 0); STG_B(0, 0, 0); STG_A(0, 1, 0); STG_B(0, 1, 0);

  const int NT = K >> 6;
  for (int t = 0; t < NT; ++t) {
    const int cur = t & 1, nbf = cur ^ 1;
    const int kN = (t + 1 < NT ? t + 1 : NT - 1) << 6;
    short8 aLo[4][2], aHi[4][2], b0f[2][2], b1f[2][2];

    // ---- ph0: A-F0 x B-G0 (acc[i][j], i0-3, j0-1)
    asm volatile("s_waitcnt vmcnt(4)\n\ts_barrier" ::: "memory");
#pragma unroll
    for (int i = 0; i < 4; ++i) {
      aLo[i][0] = *(const short8*)&As[cur][0][arow + i * 1024 + aoff0];
      aLo[i][1] = *(const short8*)&As[cur][0][arow + i * 1024 + aoff1];
    }
#pragma unroll
    for (int j = 0; j < 2; ++j) {
      b0f[j][0] = *(const short8*)&Bs[cur][0][brow + j * 1024 + aoff0];
      b0f[j][1] = *(const short8*)&Bs[cur][0][brow + j * 1024 + aoff1];
    }
    STG_A(nbf, 0, kN);
    asm volatile("s_waitcnt lgkmcnt(0)" ::: "memory");
    __builtin_amdgcn_s_setprio(1);
#pragma unroll
    for (int ks = 0; ks < 2; ++ks)
#pragma unroll
      for (int i = 0; i < 4; ++i)
#pragma unroll
        for (int j = 0; j < 2; ++j)
          acc[i][j] = __builtin_amdgcn_mfma_f32_16x16x32_bf16(
              aLo[i][ks], b0f[j][ks], acc[i][j], 0, 0, 0);
    __builtin_amdgcn_s_setprio(0);

    // ---- ph1: A-F1 x B-G0 (acc[i+4][j])
    asm volatile("s_waitcnt vmcnt(4)\n\ts_barrier" ::: "memory");
#pragma unroll
    for (int i = 0; i < 4; ++i) {
      aHi[i][0] = *(const short8*)&As[cur][1][arow + i * 1024 + aoff0];
      aHi[i][1] = *(const short8*)&As[cur][1][arow + i * 1024 + aoff1];
    }
    STG_B(nbf, 0, kN);
    asm volatile("s_waitcnt lgkmcnt(0)" ::: "memory");
    __builtin_amdgcn_s_setprio(1);
#pragma unroll
    for (int ks = 0; ks < 2; ++ks)
#pragma unroll
      for (int i = 0; i < 4; ++i)
#pragma unroll
        for (int j = 0; j < 2; ++j)
          acc[i + 4][j] = __builtin_amdgcn_mfma_f32_16x16x32_bf16(
              aHi[i][ks], b0f[j][ks], acc[i + 4][j], 0, 0, 0);
    __builtin_amdgcn_s_setprio(0);

    // ---- ph2: A-F0 x B-G1 (acc[i][j+2])
    asm volatile("s_waitcnt vmcnt(4)\n\ts_barrier" ::: "memory");
#pragma unroll
    for (int j = 0; j < 2; ++j) {
      b1f[j][0] = *(const short8*)&Bs[cur][1][brow + j * 1024 + aoff0];
      b1f[j][1] = *(const short8*)&Bs[cur][1][brow + j * 1024 + aoff1];
    }
    STG_A(nbf, 1, kN);
    asm volatile("s_waitcnt lgkmcnt(0)" ::: "memory");
    __builtin_amdgcn_s_setprio(1);
#pragma unroll
    for (int ks = 0; ks < 2; ++ks)
#pragma unroll
      for (int i = 0; i < 4; ++i)
#pragma unroll
        for (int j = 0; j < 2; ++j)
          acc[i][j + 2] = __builtin_amdgcn_mfma_f32_16x16x32_bf16(
              aLo[i][ks], b1f[j][ks], acc[i][j + 2], 0, 0, 0);
    __builtin_amdgcn_s_setprio(0);

    // ---- ph3: A-F1 x B-G1 (acc[i+4][j+2]); no new reads/waits
    __builtin_amdgcn_s_barrier();
    STG_B(nbf, 1, kN);
    __builtin_amdgcn_s_setprio(1);
#pragma unroll
    for (int ks = 0; ks < 2; ++ks)
#pragma unroll
      for (int i = 0; i < 4; ++i)
#pragma unroll
        for (int j = 0; j < 2; ++j)
          acc[i + 4][j + 2] = __builtin_amdgcn_mfma_f32_16x16x32_bf16(
              aHi[i][ks], b1f[j][ks], acc[i + 4][j + 2], 0, 0, 0);
    __builtin_amdgcn_s_setprio(0);
  }

  // drain in-flight LDS-DMA (incl. tail dummies) before epilogue/exit
  asm volatile("s_waitcnt vmcnt(0)" ::: "memory");

  if constexpr (LORA) {
    // Direct-register LoRA: rank 16 -> quads 0-1 hold ranks 0-15, quads
    // 2-3 contribute zero (A side zeroed; B also guarded for bounds).
    const unsigned short* LAz = LA + (long)blockIdx.z * batLA;
    const unsigned short* LBz = LB + (long)blockIdx.z * batLB;
    const short8 z8 = {0, 0, 0, 0, 0, 0, 0, 0};
    short8 b2[4];
#pragma unroll
    for (int j = 0; j < 4; ++j) {
      const long row = n0 + wc * 64 + j * 16 + l16;
      b2[j] = (quad < 2) ? *(const short8*)(LBz + row * 16 + quad * 8) : z8;
    }
#pragma unroll
    for (int i = 0; i < 8; ++i) {
      const long row = m0 + wr * 128 + i * 16 + l16;
      const short8 a2 =
          (quad < 2) ? *(const short8*)(LAz + row * 16 + quad * 8) : z8;
#pragma unroll
      for (int j = 0; j < 4; ++j)
        acc[i][j] = __builtin_amdgcn_mfma_f32_16x16x32_bf16(a2, b2[j], acc[i][j], 0, 0, 0);
    }
  }

#pragma unroll
  for (int i = 0; i < 8; ++i) {
    const long row = m0 + wr * 128 + i * 16 + quad * 4;
#pragma unroll
    for (int j = 0; j < 4; ++j) {
      const long col = n0 + wc * 64 + j * 16 + l16;
#pragma unroll
      for (int rr = 0; rr < 4; ++rr) {
        float val = acc[i][j][rr] * scale;
        if constexpr (OUTF32)
          ((float*)Cv)[(long)blockIdx.z * batC + (row + rr) * ldc + col] = val;
        else
          ((unsigned short*)Cv)[(long)blockIdx.z * batC + (row + rr) * ldc + col] = f2bf(val);
      }
    }
  }
#undef STG_A
#undef STG_B
}

__device__ __forceinline__ uint4 pack8(const float* x) {
  float4 a = *(const float4*)x;
  float4 b = *(const float4*)(x + 4);
  uint4 o;
  o.x = (unsigned int)f2bf(a.x) | ((unsigned int)f2bf(a.y) << 16);
  o.y = (unsigned int)f2bf(a.z) | ((unsigned int)f2bf(a.w) << 16);
  o.z = (unsigned int)f2bf(b.x) | ((unsigned int)f2bf(b.y) << 16);
  o.w = (unsigned int)f2bf(b.z) | ((unsigned int)f2bf(b.w) << 16);
  return o;
}

// pure fp32->bf16 convert of q/k/v. grid (512, 3), 16384 elems/block.
__global__ __launch_bounds__(256) void prep_qkv(
    const float* __restrict__ q, const float* __restrict__ k, const float* __restrict__ v,
    unsigned short* __restrict__ qb, unsigned short* __restrict__ kb,
    unsigned short* __restrict__ vb) {
  const float* X; unsigned short* Y;
  if (blockIdx.y == 0)      { X = q; Y = qb; }
  else if (blockIdx.y == 1) { X = k; Y = kb; }
  else                      { X = v; Y = vb; }
  const int tid = threadIdx.x;
  const long blk = (long)blockIdx.x * 16384;
#pragma unroll
  for (int it = 0; it < 8; ++it) {
    const long idx = blk + it * 2048 + tid * 8;
    *(uint4*)(Y + idx) = pack8(X + idx);
  }
}

// all weight converts in one dispatch. grid (512, 5).
__global__ __launch_bounds__(256) void cvt_all(
    const float* __restrict__ Wq, const float* __restrict__ Wk,
    const float* __restrict__ Wv, const float* __restrict__ Wo,
    const float* __restrict__ QB, const float* __restrict__ KB, const float* __restrict__ VB,
    const float* __restrict__ QA, const float* __restrict__ KA, const float* __restrict__ VA,
    unsigned short* __restrict__ wqb, unsigned short* __restrict__ wkb,
    unsigned short* __restrict__ wvb, unsigned short* __restrict__ wob,
    unsigned short* __restrict__ Bqb, unsigned short* __restrict__ Bkb, unsigned short* __restrict__ Bvb,
    unsigned short* __restrict__ Aqb, unsigned short* __restrict__ Akb, unsigned short* __restrict__ Avb) {
  if (blockIdx.y < 4) {
    const float* x; unsigned short* y;
    switch (blockIdx.y) {
      case 0: x = Wq; y = wqb; break;
      case 1: x = Wk; y = wkb; break;
      case 2: x = Wv; y = wvb; break;
      default: x = Wo; y = wob; break;
    }
    const long i = ((long)blockIdx.x * 256 + threadIdx.x) * 8;
    *(uint4*)(y + i) = pack8(x + i);
  } else {
    if (blockIdx.x >= 48) return;
    const int mat = blockIdx.x >> 3, sub = blockIdx.x & 7;
    const float* x; unsigned short* y;
    switch (mat) {
      case 0: x = QB; y = Bqb; break;
      case 1: x = KB; y = Bkb; break;
      case 2: x = VB; y = Bvb; break;
      case 3: x = QA; y = Aqb; break;
      case 4: x = KA; y = Akb; break;
      default: x = VA; y = Avb; break;
    }
    const long i = ((long)sub * 256 + threadIdx.x) * 8;
    *(uint4*)(y + i) = pack8(x + i);
  }
}

// T[8192][16] = Xb @ Am^T via MFMA. grid (128, 3): 64 rows/block, 16/wave.
__global__ __launch_bounds__(256) void lora_t_mfma(
    const unsigned short* __restrict__ qb, const unsigned short* __restrict__ kb,
    const unsigned short* __restrict__ vb,
    const unsigned short* __restrict__ Aq, const unsigned short* __restrict__ Ak,
    const unsigned short* __restrict__ Av,
    unsigned short* __restrict__ Tq, unsigned short* __restrict__ Tk,
    unsigned short* __restrict__ Tv) {
  const unsigned short* X; const unsigned short* Am; unsigned short* T;
  if (blockIdx.y == 0)      { X = qb; Am = Aq; T = Tq; }
  else if (blockIdx.y == 1) { X = kb; Am = Ak; T = Tk; }
  else                      { X = vb; Am = Av; T = Tv; }
  const int tid = threadIdx.x, wave = tid >> 6, lane = tid & 63;
  const int quad = lane >> 4, l16 = lane & 15;
  const long m0 = (long)blockIdx.x * 64 + wave * 16;
  floatx4 acc = (floatx4){0.f, 0.f, 0.f, 0.f};
  const unsigned short* xp = X + (m0 + l16) * 1024 + quad * 8;
  const unsigned short* ap = Am + (long)l16 * 1024 + quad * 8;
#pragma unroll 4
  for (int k0 = 0; k0 < 1024; k0 += 32) {
    short8 af = *(const short8*)(xp + k0);
    short8 bf = *(const short8*)(ap + k0);
    acc = __builtin_amdgcn_mfma_f32_16x16x32_bf16(af, bf, acc, 0, 0, 0);
  }
#pragma unroll
  for (int rr = 0; rr < 4; ++rr)
    T[(m0 + quad * 4 + rr) * 16 + l16] = f2bf(acc[rr]);
}

// in-place row softmax over 2048 bf16 scores; one block per row
__global__ __launch_bounds__(256) void softmax_kernel(unsigned short* __restrict__ S) {
  const long base = (long)blockIdx.x * 2048;
  const int tid = threadIdx.x;
  const int lane = tid & 63, wave = tid >> 6;
  __shared__ float redm[4], reds[4];
  uint4 raw = *(const uint4*)(S + base + tid * 8);
  unsigned int w[4] = {raw.x, raw.y, raw.z, raw.w};
  float v[8];
#pragma unroll
  for (int i = 0; i < 4; ++i) {
    v[2 * i]     = bf2f((unsigned short)(w[i] & 0xffffu));
    v[2 * i + 1] = bf2f((unsigned short)(w[i] >> 16));
  }
  float m = v[0];
#pragma unroll
  for (int i = 1; i < 8; ++i) m = fmaxf(m, v[i]);
  for (int off = 32; off >= 1; off >>= 1) m = fmaxf(m, __shfl_xor(m, off, 64));
  if (lane == 0) redm[wave] = m;
  __syncthreads();
  m = fmaxf(fmaxf(redm[0], redm[1]), fmaxf(redm[2], redm[3]));
  float e[8], s = 0.f;
#pragma unroll
  for (int i = 0; i < 8; ++i) { e[i] = __expf(v[i] - m); s += e[i]; }
  for (int off = 32; off >= 1; off >>= 1) s += __shfl_xor(s, off, 64);
  if (lane == 0) reds[wave] = s;
  __syncthreads();
  s = reds[0] + reds[1] + reds[2] + reds[3];
  const float inv = 1.0f / s;
  uint4 o;
  o.x = (unsigned int)f2bf(e[0] * inv) | ((unsigned int)f2bf(e[1] * inv) << 16);
  o.y = (unsigned int)f2bf(e[2] * inv) | ((unsigned int)f2bf(e[3] * inv) << 16);
  o.z = (unsigned int)f2bf(e[4] * inv) | ((unsigned int)f2bf(e[5] * inv) << 16);
  o.w = (unsigned int)f2bf(e[6] * inv) | ((unsigned int)f2bf(e[7] * inv) << 16);
  *(uint4*)(S + base + tid * 8) = o;
}

extern "C" void kernel_launch(void* const* d_in, const int* in_sizes, int n_in,
                              void* d_out, int out_size, void* d_ws, size_t ws_size,
                              hipStream_t stream) {
  const float* q  = (const float*)d_in[0];
  const float* k  = (const float*)d_in[1];
  const float* v  = (const float*)d_in[2];
  const float* Wq = (const float*)d_in[3];
  const float* Wk = (const float*)d_in[4];
  const float* Wv = (const float*)d_in[5];
  const float* QA = (const float*)d_in[6];
  const float* QB = (const float*)d_in[7];
  const float* KA = (const float*)d_in[8];
  const float* KB = (const float*)d_in[9];
  const float* VA = (const float*)d_in[10];
  const float* VB = (const float*)d_in[11];
  const float* Wo = (const float*)d_in[12];

  unsigned short* W = (unsigned short*)d_ws;
  const long SEe = (long)8192 * 1024;  // 8388608
  unsigned short* qb  = W;             // dead after Q-proj -> scores low half
  unsigned short* kb  = W + SEe;
  unsigned short* vb  = W + 2 * SEe;   // dead after V-proj -> attn buffer
  unsigned short* Qp  = W + 3 * SEe;
  unsigned short* Kp  = W + 4 * SEe;
  unsigned short* VT  = W + 5 * SEe;   // [1024][8192] = V^T
  unsigned short* wqb = W + 6 * SEe;
  unsigned short* wkb = wqb + 1048576;
  unsigned short* wvb = wkb + 1048576;
  unsigned short* wob = wvb + 1048576;
  unsigned short* Bqb = wob + 1048576;
  unsigned short* Bkb = Bqb + 16384;
  unsigned short* Bvb = Bkb + 16384;
  unsigned short* Aqb = Bvb + 16384;
  unsigned short* Akb = Aqb + 16384;
  unsigned short* Avb = Akb + 16384;
  unsigned short* Tq  = Avb + 16384;   // [8192][16]
  unsigned short* Tk  = Tq + 131072;
  unsigned short* Tv  = Tk + 131072;
  unsigned short* scores = W;          // [4][2048][2048] bf16, aliases qb+kb
  unsigned short* attn   = vb;         // [8192][1024] bf16, aliases vb

  dim3 blk(256, 1, 1), blk5(512, 1, 1);
  prep_qkv<<<dim3(512, 3, 1), blk, 0, stream>>>(q, k, v, qb, kb, vb);
  cvt_all<<<dim3(512, 5, 1), blk, 0, stream>>>(Wq, Wk, Wv, Wo, QB, KB, VB, QA, KA, VA,
                                               wqb, wkb, wvb, wob, Bqb, Bkb, Bvb, Aqb, Akb, Avb);
  lora_t_mfma<<<dim3(128, 3, 1), blk, 0, stream>>>(qb, kb, vb, Aqb, Akb, Avb, Tq, Tk, Tv);

  // Q = qb@Wq^T + Tq@Bq^T ; K likewise (z batches; M=8192,N=1024,K=1024)
  gemm8p<true, false, true><<<dim3(4, 32, 2), blk5, 0, stream>>>(
      qb, wqb, Qp, Tq, Bqb, 1024, 1024, 1024, 1024, 1.0f,
      SEe, 1048576, SEe, 131072, 16384);
  // VT = Wv@vb^T + Bv@Tv^T  (M=1024,N=8192): OWNN
  gemm8p<true, false, false><<<dim3(32, 4, 1), blk5, 0, stream>>>(
      wvb, vb, VT, Bvb, Tv, 1024, 1024, 8192, 1024, 1.0f, 0, 0, 0, 0, 0);
  // scores = Qp@Kp^T / 32   (batched, M=N=2048,K=1024)
  gemm8p<false, false, true><<<dim3(8, 8, 4), blk5, 0, stream>>>(
      Qp, Kp, scores, nullptr, nullptr, 1024, 1024, 2048, 1024, 0.03125f,
      (long)S_LEN * E_DIM, (long)S_LEN * E_DIM, (long)S_LEN * S_LEN, 0, 0);
  softmax_kernel<<<8192, blk, 0, stream>>>(scores);
  // attn_out = P@V = P@(VT)^T  (batched, M=2048,N=1024,K=2048)
  gemm8p<false, false, true><<<dim3(4, 8, 4), blk5, 0, stream>>>(
      scores, VT, attn, nullptr, nullptr, 2048, 8192, 1024, 2048, 1.0f,
      (long)S_LEN * S_LEN, (long)S_LEN, (long)S_LEN * E_DIM, 0, 0);
  // final = attn@Wo^T -> fp32 d_out  (M=8192,N=1024,K=1024)
  gemm8p<false, true, true><<<dim3(4, 32, 1), blk5, 0, stream>>>(
      attn, wob, d_out, nullptr, nullptr, 1024, 1024, 1024, 1024, 1.0f, 0, 0, 0, 0, 0);
}

// Round 7
// 370.532 us; speedup vs baseline: 1.2445x; 1.0265x over previous
//
#include <hip/hip_runtime.h>

// LoRA attention: B=4, S=2048, E=1024, R=16, fp32 in/out.
// R12 changes vs R11 (380.3us):
//  - R11 confirmed the 4-phase counted-vmcnt structure: per-CU eff 2.1 ->
//    4.6 TF/CU (47%). But attn/V-proj/final ran on HALF the chip (128 wg of
//    256^2 tiles; Occupancy 9.8%). Added gemm128: BM=128 x BN=256, same
//    4-phase schedule, 96KB LDS, 256 wg -> full chip for those three.
//    (R7's BN=128 failure was the 2-phase structure's per-CU collapse;
//    that limiter is gone now.)
//  - gemm128 staging: A-halves 64 rows (1 gld_lds/thread), B-halves 128
//    rows (2 gld_lds/thread); 6 loads/tile; phases stage AF0|BG0|AF1|BG1.
//    Entry waits vmcnt(3) at ph0/ph1/ph2 (in-order queue: 6/4/5
//    outstanding, each wait retires exactly the needed half), ph3 waitless.
//  - Q/K proj + scores keep proven gemm8p (256^2, already 256 wg).
// Carried: XOR-swizzled row-major LDS (both-sides), XCD swizzle, counted
// vmcnt never 0 in loop, setprio around MFMA, direct-register LoRA epilogue.

#define S_LEN 2048
#define E_DIM 1024

typedef __attribute__((ext_vector_type(8))) short short8;
typedef __attribute__((ext_vector_type(4))) float floatx4;

__device__ __forceinline__ unsigned short f2bf(float f) {
  union { float f; unsigned int u; } x; x.f = f;
  return (unsigned short)((x.u + 0x7fffu + ((x.u >> 16) & 1u)) >> 16);  // RNE
}
__device__ __forceinline__ float bf2f(unsigned short h) {
  union { unsigned int u; float f; } x; x.u = ((unsigned int)h) << 16;
  return x.f;
}

__device__ __forceinline__ void gld_lds16(const unsigned short* g, unsigned short* l) {
  __builtin_amdgcn_global_load_lds(
      (const __attribute__((address_space(1))) unsigned int*)(const void*)g,
      (__attribute__((address_space(3))) unsigned int*)(void*)l,
      16, 0, 0);
}

// ---------------- gemm8p: 256^2 tile, BK=64, 4-phase (R11, proven) --------
template<bool LORA, bool OUTF32, bool OWNM>
__global__ __launch_bounds__(512, 2) void gemm8p(
    const unsigned short* __restrict__ A, const unsigned short* __restrict__ B,
    void* __restrict__ Cv,
    const unsigned short* __restrict__ LA, const unsigned short* __restrict__ LB,
    long lda, long ldb, long ldc, int K, float scale,
    long batA, long batB, long batC, long batLA, long batLB) {
  __shared__ alignas(16) unsigned short As[2][2][8192];
  __shared__ alignas(16) unsigned short Bs[2][2][8192];

  const int tid  = threadIdx.x;
  const int wave = tid >> 6, lane = tid & 63;
  const int quad = lane >> 4, l16 = lane & 15;
  const int wr = wave >> 2, wc = wave & 3;  // 2M x 4N waves, each 128x64

  const int Nx = (int)gridDim.x, Ny = (int)gridDim.y;
  const int wg2 = (int)blockIdx.x + Nx * (int)blockIdx.y;
  const int xcd = wg2 & 7, ii = wg2 >> 3;
  int bx, by;
  if constexpr (OWNM) {
    const int lg = 31 - __clz(Nx);
    by = xcd * (Ny >> 3) + (ii >> lg);
    bx = ii & (Nx - 1);
  } else {
    const int lg = 31 - __clz(Ny);
    bx = xcd * (Nx >> 3) + (ii >> lg);
    by = ii & (Ny - 1);
  }
  const long m0 = (long)by * 256;
  const long n0 = (long)bx * 256;
  const unsigned short* Az = A + (long)blockIdx.z * batA;
  const unsigned short* Bz = B + (long)blockIdx.z * batB;

  floatx4 acc[8][4];
#pragma unroll
  for (int i = 0; i < 8; ++i)
#pragma unroll
    for (int j = 0; j < 4; ++j) acc[i][j] = (floatx4){0.f, 0.f, 0.f, 0.f};

  const int lr = tid >> 3;                 // 0..63 (chunk2: +64)
  const int sp = (tid & 7) ^ (lr & 7);     // inverse-swizzled source slot
  const unsigned short* aS = Az + (m0 + lr) * lda + sp * 8;
  const unsigned short* bS = Bz + (n0 + (lr >> 5) * 64 + (lr & 31)) * ldb + sp * 8;

#define STG_A(bf, F, k0)                                                     \
  do {                                                                       \
    gld_lds16(aS + (long)((F) * 64) * lda + (k0), &As[bf][F][tid * 8]);      \
    gld_lds16(aS + (long)((F) * 64 + 128) * lda + (k0),                      \
              &As[bf][F][4096 + tid * 8]);                                   \
  } while (0)
#define STG_B(bf, G, k0)                                                     \
  do {                                                                       \
    gld_lds16(bS + (long)((G) * 32) * ldb + (k0), &Bs[bf][G][tid * 8]);      \
    gld_lds16(bS + (long)((G) * 32 + 128) * ldb + (k0),                      \
              &Bs[bf][G][4096 + tid * 8]);                                   \
  } while (0)

  const int xo    = (l16 & 7) << 4;
  const int aoff0 = ((quad * 16) ^ xo) >> 1;
  const int aoff1 = ((64 + quad * 16) ^ xo) >> 1;
  const int arow  = wr * 4096 + l16 * 64;
  const int brow  = wc * 2048 + l16 * 64;

  STG_A(0, 0, 0); STG_B(0, 0, 0); STG_A(0, 1, 0); STG_B(0, 1, 0);

  const int NT = K >> 6;
  for (int t = 0; t < NT; ++t) {
    const int cur = t & 1, nbf = cur ^ 1;
    const int kN = (t + 1 < NT ? t + 1 : NT - 1) << 6;
    short8 aLo[4][2], aHi[4][2], b0f[2][2], b1f[2][2];

    asm volatile("s_waitcnt vmcnt(4)\n\ts_barrier" ::: "memory");
#pragma unroll
    for (int i = 0; i < 4; ++i) {
      aLo[i][0] = *(const short8*)&As[cur][0][arow + i * 1024 + aoff0];
      aLo[i][1] = *(const short8*)&As[cur][0][arow + i * 1024 + aoff1];
    }
#pragma unroll
    for (int j = 0; j < 2; ++j) {
      b0f[j][0] = *(const short8*)&Bs[cur][0][brow + j * 1024 + aoff0];
      b0f[j][1] = *(const short8*)&Bs[cur][0][brow + j * 1024 + aoff1];
    }
    STG_A(nbf, 0, kN);
    asm volatile("s_waitcnt lgkmcnt(0)" ::: "memory");
    __builtin_amdgcn_s_setprio(1);
#pragma unroll
    for (int ks = 0; ks < 2; ++ks)
#pragma unroll
      for (int i = 0; i < 4; ++i)
#pragma unroll
        for (int j = 0; j < 2; ++j)
          acc[i][j] = __builtin_amdgcn_mfma_f32_16x16x32_bf16(
              aLo[i][ks], b0f[j][ks], acc[i][j], 0, 0, 0);
    __builtin_amdgcn_s_setprio(0);

    asm volatile("s_waitcnt vmcnt(4)\n\ts_barrier" ::: "memory");
#pragma unroll
    for (int i = 0; i < 4; ++i) {
      aHi[i][0] = *(const short8*)&As[cur][1][arow + i * 1024 + aoff0];
      aHi[i][1] = *(const short8*)&As[cur][1][arow + i * 1024 + aoff1];
    }
    STG_B(nbf, 0, kN);
    asm volatile("s_waitcnt lgkmcnt(0)" ::: "memory");
    __builtin_amdgcn_s_setprio(1);
#pragma unroll
    for (int ks = 0; ks < 2; ++ks)
#pragma unroll
      for (int i = 0; i < 4; ++i)
#pragma unroll
        for (int j = 0; j < 2; ++j)
          acc[i + 4][j] = __builtin_amdgcn_mfma_f32_16x16x32_bf16(
              aHi[i][ks], b0f[j][ks], acc[i + 4][j], 0, 0, 0);
    __builtin_amdgcn_s_setprio(0);

    asm volatile("s_waitcnt vmcnt(4)\n\ts_barrier" ::: "memory");
#pragma unroll
    for (int j = 0; j < 2; ++j) {
      b1f[j][0] = *(const short8*)&Bs[cur][1][brow + j * 1024 + aoff0];
      b1f[j][1] = *(const short8*)&Bs[cur][1][brow + j * 1024 + aoff1];
    }
    STG_A(nbf, 1, kN);
    asm volatile("s_waitcnt lgkmcnt(0)" ::: "memory");
    __builtin_amdgcn_s_setprio(1);
#pragma unroll
    for (int ks = 0; ks < 2; ++ks)
#pragma unroll
      for (int i = 0; i < 4; ++i)
#pragma unroll
        for (int j = 0; j < 2; ++j)
          acc[i][j + 2] = __builtin_amdgcn_mfma_f32_16x16x32_bf16(
              aLo[i][ks], b1f[j][ks], acc[i][j + 2], 0, 0, 0);
    __builtin_amdgcn_s_setprio(0);

    __builtin_amdgcn_s_barrier();
    STG_B(nbf, 1, kN);
    __builtin_amdgcn_s_setprio(1);
#pragma unroll
    for (int ks = 0; ks < 2; ++ks)
#pragma unroll
      for (int i = 0; i < 4; ++i)
#pragma unroll
        for (int j = 0; j < 2; ++j)
          acc[i + 4][j + 2] = __builtin_amdgcn_mfma_f32_16x16x32_bf16(
              aHi[i][ks], b1f[j][ks], acc[i + 4][j + 2], 0, 0, 0);
    __builtin_amdgcn_s_setprio(0);
  }

  asm volatile("s_waitcnt vmcnt(0)" ::: "memory");

  if constexpr (LORA) {
    const unsigned short* LAz = LA + (long)blockIdx.z * batLA;
    const unsigned short* LBz = LB + (long)blockIdx.z * batLB;
    const short8 z8 = {0, 0, 0, 0, 0, 0, 0, 0};
    short8 b2[4];
#pragma unroll
    for (int j = 0; j < 4; ++j) {
      const long row = n0 + wc * 64 + j * 16 + l16;
      b2[j] = (quad < 2) ? *(const short8*)(LBz + row * 16 + quad * 8) : z8;
    }
#pragma unroll
    for (int i = 0; i < 8; ++i) {
      const long row = m0 + wr * 128 + i * 16 + l16;
      const short8 a2 =
          (quad < 2) ? *(const short8*)(LAz + row * 16 + quad * 8) : z8;
#pragma unroll
      for (int j = 0; j < 4; ++j)
        acc[i][j] = __builtin_amdgcn_mfma_f32_16x16x32_bf16(a2, b2[j], acc[i][j], 0, 0, 0);
    }
  }

#pragma unroll
  for (int i = 0; i < 8; ++i) {
    const long row = m0 + wr * 128 + i * 16 + quad * 4;
#pragma unroll
    for (int j = 0; j < 4; ++j) {
      const long col = n0 + wc * 64 + j * 16 + l16;
#pragma unroll
      for (int rr = 0; rr < 4; ++rr) {
        float val = acc[i][j][rr] * scale;
        if constexpr (OUTF32)
          ((float*)Cv)[(long)blockIdx.z * batC + (row + rr) * ldc + col] = val;
        else
          ((unsigned short*)Cv)[(long)blockIdx.z * batC + (row + rr) * ldc + col] = f2bf(val);
      }
    }
  }
#undef STG_A
#undef STG_B
}

// ---------------- gemm128: 128x256 tile, BK=64, 4-phase, 256-wg fill ------
// Waves 2M x 4N, each 64x64 (acc[4][4]). A halves F: 64 rows
// {F*32..F*32+31, 64+F*32..}; B halves G: 128 rows (n-row = (lr>>5)*64 +
// (lr&31) + G*32). 6 loads/tile staged AF0@ph0, BG0@ph1(2), AF1@ph2,
// BG1@ph3(2). Entry vmcnt(3) at ph0/ph1/ph2 (queue 6/4/5 -> retires the
// needed half exactly), ph3 waitless. LDS 96KB.
template<bool LORA, bool OUTF32, bool OWNM>
__global__ __launch_bounds__(512, 2) void gemm128(
    const unsigned short* __restrict__ A, const unsigned short* __restrict__ B,
    void* __restrict__ Cv,
    const unsigned short* __restrict__ LA, const unsigned short* __restrict__ LB,
    long lda, long ldb, long ldc, int K, float scale,
    long batA, long batB, long batC, long batLA, long batLB) {
  __shared__ alignas(16) unsigned short As[2][2][4096];  // [buf][half][64x64]
  __shared__ alignas(16) unsigned short Bs[2][2][8192];  // [buf][half][128x64]

  const int tid  = threadIdx.x;
  const int wave = tid >> 6, lane = tid & 63;
  const int quad = lane >> 4, l16 = lane & 15;
  const int wr = wave >> 2, wc = wave & 3;  // 2M x 4N waves, each 64x64

  const int Nx = (int)gridDim.x, Ny = (int)gridDim.y;
  const int wg2 = (int)blockIdx.x + Nx * (int)blockIdx.y;
  const int xcd = wg2 & 7, ii = wg2 >> 3;
  int bx, by;
  if constexpr (OWNM) {
    const int lg = 31 - __clz(Nx);
    by = xcd * (Ny >> 3) + (ii >> lg);
    bx = ii & (Nx - 1);
  } else {
    const int lg = 31 - __clz(Ny);
    bx = xcd * (Nx >> 3) + (ii >> lg);
    by = ii & (Ny - 1);
  }
  const long m0 = (long)by * 128;
  const long n0 = (long)bx * 256;
  const unsigned short* Az = A + (long)blockIdx.z * batA;
  const unsigned short* Bz = B + (long)blockIdx.z * batB;

  floatx4 acc[4][4];
#pragma unroll
  for (int i = 0; i < 4; ++i)
#pragma unroll
    for (int j = 0; j < 4; ++j) acc[i][j] = (floatx4){0.f, 0.f, 0.f, 0.f};

  const int lr = tid >> 3;                 // 0..63
  const int sp = (tid & 7) ^ (lr & 7);
  // A half F: global row m0 + (lr>>5)*64 + (lr&31) + F*32
  const unsigned short* aS = Az + (m0 + (lr >> 5) * 64 + (lr & 31)) * lda + sp * 8;
  // B half G chunks c=tid (lr) and c=tid+512 (lr+64); (lr+64)&7 == lr&7.
  const unsigned short* bS  = Bz + (n0 + (lr >> 5) * 64 + (lr & 31)) * ldb + sp * 8;
  const unsigned short* bS2 = Bz + (n0 + ((lr + 64) >> 5) * 64 + ((lr + 64) & 31)) * ldb + sp * 8;

#define STG_A(bf, F, k0)                                                     \
  gld_lds16(aS + (long)((F) * 32) * lda + (k0), &As[bf][F][tid * 8])
#define STG_B(bf, G, k0)                                                     \
  do {                                                                       \
    gld_lds16(bS + (long)((G) * 32) * ldb + (k0), &Bs[bf][G][tid * 8]);      \
    gld_lds16(bS2 + (long)((G) * 32) * ldb + (k0),                           \
              &Bs[bf][G][4096 + tid * 8]);                                   \
  } while (0)

  const int xo    = (l16 & 7) << 4;
  const int aoff0 = ((quad * 16) ^ xo) >> 1;
  const int aoff1 = ((64 + quad * 16) ^ xo) >> 1;
  const int arow  = wr * 2048 + l16 * 64;  // + (i&1)*1024, half = i>>1
  const int brow  = wc * 2048 + l16 * 64;  // + (j&1)*1024, half = j>>1

  // prologue: tile 0 halves in consumption order (6 loads).
  STG_A(0, 0, 0); STG_B(0, 0, 0); STG_A(0, 1, 0); STG_B(0, 1, 0);

  const int NT = K >> 6;
  for (int t = 0; t < NT; ++t) {
    const int cur = t & 1, nbf = cur ^ 1;
    const int kN = (t + 1 < NT ? t + 1 : NT - 1) << 6;
    short8 aF0[2][2], aF1[2][2], bG0[2][2], bG1[2][2];

    // ---- ph0: AF0 x BG0 -> acc[0..1][0..1]
    asm volatile("s_waitcnt vmcnt(3)\n\ts_barrier" ::: "memory");
#pragma unroll
    for (int i = 0; i < 2; ++i) {
      aF0[i][0] = *(const short8*)&As[cur][0][arow + i * 1024 + aoff0];
      aF0[i][1] = *(const short8*)&As[cur][0][arow + i * 1024 + aoff1];
    }
#pragma unroll
    for (int j = 0; j < 2; ++j) {
      bG0[j][0] = *(const short8*)&Bs[cur][0][brow + j * 1024 + aoff0];
      bG0[j][1] = *(const short8*)&Bs[cur][0][brow + j * 1024 + aoff1];
    }
    STG_A(nbf, 0, kN);
    asm volatile("s_waitcnt lgkmcnt(0)" ::: "memory");
    __builtin_amdgcn_s_setprio(1);
#pragma unroll
    for (int ks = 0; ks < 2; ++ks)
#pragma unroll
      for (int i = 0; i < 2; ++i)
#pragma unroll
        for (int j = 0; j < 2; ++j)
          acc[i][j] = __builtin_amdgcn_mfma_f32_16x16x32_bf16(
              aF0[i][ks], bG0[j][ks], acc[i][j], 0, 0, 0);
    __builtin_amdgcn_s_setprio(0);

    // ---- ph1: AF1 x BG0 -> acc[2..3][0..1]
    asm volatile("s_waitcnt vmcnt(3)\n\ts_barrier" ::: "memory");
#pragma unroll
    for (int i = 0; i < 2; ++i) {
      aF1[i][0] = *(const short8*)&As[cur][1][arow + i * 1024 + aoff0];
      aF1[i][1] = *(const short8*)&As[cur][1][arow + i * 1024 + aoff1];
    }
    STG_B(nbf, 0, kN);
    asm volatile("s_waitcnt lgkmcnt(0)" ::: "memory");
    __builtin_amdgcn_s_setprio(1);
#pragma unroll
    for (int ks = 0; ks < 2; ++ks)
#pragma unroll
      for (int i = 0; i < 2; ++i)
#pragma unroll
        for (int j = 0; j < 2; ++j)
          acc[i + 2][j] = __builtin_amdgcn_mfma_f32_16x16x32_bf16(
              aF1[i][ks], bG0[j][ks], acc[i + 2][j], 0, 0, 0);
    __builtin_amdgcn_s_setprio(0);

    // ---- ph2: AF0 x BG1 -> acc[0..1][2..3]
    asm volatile("s_waitcnt vmcnt(3)\n\ts_barrier" ::: "memory");
#pragma unroll
    for (int j = 0; j < 2; ++j) {
      bG1[j][0] = *(const short8*)&Bs[cur][1][brow + j * 1024 + aoff0];
      bG1[j][1] = *(const short8*)&Bs[cur][1][brow + j * 1024 + aoff1];
    }
    STG_A(nbf, 1, kN);
    asm volatile("s_waitcnt lgkmcnt(0)" ::: "memory");
    __builtin_amdgcn_s_setprio(1);
#pragma unroll
    for (int ks = 0; ks < 2; ++ks)
#pragma unroll
      for (int i = 0; i < 2; ++i)
#pragma unroll
        for (int j = 0; j < 2; ++j)
          acc[i][j + 2] = __builtin_amdgcn_mfma_f32_16x16x32_bf16(
              aF0[i][ks], bG1[j][ks], acc[i][j + 2], 0, 0, 0);
    __builtin_amdgcn_s_setprio(0);

    // ---- ph3: AF1 x BG1 -> acc[2..3][2..3]; no wait, stage BG1'
    __builtin_amdgcn_s_barrier();
    STG_B(nbf, 1, kN);
    __builtin_amdgcn_s_setprio(1);
#pragma unroll
    for (int ks = 0; ks < 2; ++ks)
#pragma unroll
      for (int i = 0; i < 2; ++i)
#pragma unroll
        for (int j = 0; j < 2; ++j)
          acc[i + 2][j + 2] = __builtin_amdgcn_mfma_f32_16x16x32_bf16(
              aF1[i][ks], bG1[j][ks], acc[i + 2][j + 2], 0, 0, 0);
    __builtin_amdgcn_s_setprio(0);
  }

  asm volatile("s_waitcnt vmcnt(0)" ::: "memory");

  if constexpr (LORA) {
    const unsigned short* LAz = LA + (long)blockIdx.z * batLA;
    const unsigned short* LBz = LB + (long)blockIdx.z * batLB;
    const short8 z8 = {0, 0, 0, 0, 0, 0, 0, 0};
    short8 b2[4];
#pragma unroll
    for (int j = 0; j < 4; ++j) {
      const long row = n0 + wc * 64 + j * 16 + l16;
      b2[j] = (quad < 2) ? *(const short8*)(LBz + row * 16 + quad * 8) : z8;
    }
#pragma unroll
    for (int i = 0; i < 4; ++i) {
      const long row = m0 + wr * 64 + i * 16 + l16;
      const short8 a2 =
          (quad < 2) ? *(const short8*)(LAz + row * 16 + quad * 8) : z8;
#pragma unroll
      for (int j = 0; j < 4; ++j)
        acc[i][j] = __builtin_amdgcn_mfma_f32_16x16x32_bf16(a2, b2[j], acc[i][j], 0, 0, 0);
    }
  }

#pragma unroll
  for (int i = 0; i < 4; ++i) {
    const long row = m0 + wr * 64 + i * 16 + quad * 4;
#pragma unroll
    for (int j = 0; j < 4; ++j) {
      const long col = n0 + wc * 64 + j * 16 + l16;
#pragma unroll
      for (int rr = 0; rr < 4; ++rr) {
        float val = acc[i][j][rr] * scale;
        if constexpr (OUTF32)
          ((float*)Cv)[(long)blockIdx.z * batC + (row + rr) * ldc + col] = val;
        else
          ((unsigned short*)Cv)[(long)blockIdx.z * batC + (row + rr) * ldc + col] = f2bf(val);
      }
    }
  }
#undef STG_A
#undef STG_B
}

__device__ __forceinline__ uint4 pack8(const float* x) {
  float4 a = *(const float4*)x;
  float4 b = *(const float4*)(x + 4);
  uint4 o;
  o.x = (unsigned int)f2bf(a.x) | ((unsigned int)f2bf(a.y) << 16);
  o.y = (unsigned int)f2bf(a.z) | ((unsigned int)f2bf(a.w) << 16);
  o.z = (unsigned int)f2bf(b.x) | ((unsigned int)f2bf(b.y) << 16);
  o.w = (unsigned int)f2bf(b.z) | ((unsigned int)f2bf(b.w) << 16);
  return o;
}

// pure fp32->bf16 convert of q/k/v. grid (512, 3), 16384 elems/block.
__global__ __launch_bounds__(256) void prep_qkv(
    const float* __restrict__ q, const float* __restrict__ k, const float* __restrict__ v,
    unsigned short* __restrict__ qb, unsigned short* __restrict__ kb,
    unsigned short* __restrict__ vb) {
  const float* X; unsigned short* Y;
  if (blockIdx.y == 0)      { X = q; Y = qb; }
  else if (blockIdx.y == 1) { X = k; Y = kb; }
  else                      { X = v; Y = vb; }
  const int tid = threadIdx.x;
  const long blk = (long)blockIdx.x * 16384;
#pragma unroll
  for (int it = 0; it < 8; ++it) {
    const long idx = blk + it * 2048 + tid * 8;
    *(uint4*)(Y + idx) = pack8(X + idx);
  }
}

// all weight converts in one dispatch. grid (512, 5).
__global__ __launch_bounds__(256) void cvt_all(
    const float* __restrict__ Wq, const float* __restrict__ Wk,
    const float* __restrict__ Wv, const float* __restrict__ Wo,
    const float* __restrict__ QB, const float* __restrict__ KB, const float* __restrict__ VB,
    const float* __restrict__ QA, const float* __restrict__ KA, const float* __restrict__ VA,
    unsigned short* __restrict__ wqb, unsigned short* __restrict__ wkb,
    unsigned short* __restrict__ wvb, unsigned short* __restrict__ wob,
    unsigned short* __restrict__ Bqb, unsigned short* __restrict__ Bkb, unsigned short* __restrict__ Bvb,
    unsigned short* __restrict__ Aqb, unsigned short* __restrict__ Akb, unsigned short* __restrict__ Avb) {
  if (blockIdx.y < 4) {
    const float* x; unsigned short* y;
    switch (blockIdx.y) {
      case 0: x = Wq; y = wqb; break;
      case 1: x = Wk; y = wkb; break;
      case 2: x = Wv; y = wvb; break;
      default: x = Wo; y = wob; break;
    }
    const long i = ((long)blockIdx.x * 256 + threadIdx.x) * 8;
    *(uint4*)(y + i) = pack8(x + i);
  } else {
    if (blockIdx.x >= 48) return;
    const int mat = blockIdx.x >> 3, sub = blockIdx.x & 7;
    const float* x; unsigned short* y;
    switch (mat) {
      case 0: x = QB; y = Bqb; break;
      case 1: x = KB; y = Bkb; break;
      case 2: x = VB; y = Bvb; break;
      case 3: x = QA; y = Aqb; break;
      case 4: x = KA; y = Akb; break;
      default: x = VA; y = Avb; break;
    }
    const long i = ((long)sub * 256 + threadIdx.x) * 8;
    *(uint4*)(y + i) = pack8(x + i);
  }
}

// T[8192][16] = Xb @ Am^T via MFMA. grid (128, 3): 64 rows/block, 16/wave.
__global__ __launch_bounds__(256) void lora_t_mfma(
    const unsigned short* __restrict__ qb, const unsigned short* __restrict__ kb,
    const unsigned short* __restrict__ vb,
    const unsigned short* __restrict__ Aq, const unsigned short* __restrict__ Ak,
    const unsigned short* __restrict__ Av,
    unsigned short* __restrict__ Tq, unsigned short* __restrict__ Tk,
    unsigned short* __restrict__ Tv) {
  const unsigned short* X; const unsigned short* Am; unsigned short* T;
  if (blockIdx.y == 0)      { X = qb; Am = Aq; T = Tq; }
  else if (blockIdx.y == 1) { X = kb; Am = Ak; T = Tk; }
  else                      { X = vb; Am = Av; T = Tv; }
  const int tid = threadIdx.x, wave = tid >> 6, lane = tid & 63;
  const int quad = lane >> 4, l16 = lane & 15;
  const long m0 = (long)blockIdx.x * 64 + wave * 16;
  floatx4 acc = (floatx4){0.f, 0.f, 0.f, 0.f};
  const unsigned short* xp = X + (m0 + l16) * 1024 + quad * 8;
  const unsigned short* ap = Am + (long)l16 * 1024 + quad * 8;
#pragma unroll 4
  for (int k0 = 0; k0 < 1024; k0 += 32) {
    short8 af = *(const short8*)(xp + k0);
    short8 bf = *(const short8*)(ap + k0);
    acc = __builtin_amdgcn_mfma_f32_16x16x32_bf16(af, bf, acc, 0, 0, 0);
  }
#pragma unroll
  for (int rr = 0; rr < 4; ++rr)
    T[(m0 + quad * 4 + rr) * 16 + l16] = f2bf(acc[rr]);
}

// in-place row softmax over 2048 bf16 scores; one block per row
__global__ __launch_bounds__(256) void softmax_kernel(unsigned short* __restrict__ S) {
  const long base = (long)blockIdx.x * 2048;
  const int tid = threadIdx.x;
  const int lane = tid & 63, wave = tid >> 6;
  __shared__ float redm[4], reds[4];
  uint4 raw = *(const uint4*)(S + base + tid * 8);
  unsigned int w[4] = {raw.x, raw.y, raw.z, raw.w};
  float v[8];
#pragma unroll
  for (int i = 0; i < 4; ++i) {
    v[2 * i]     = bf2f((unsigned short)(w[i] & 0xffffu));
    v[2 * i + 1] = bf2f((unsigned short)(w[i] >> 16));
  }
  float m = v[0];
#pragma unroll
  for (int i = 1; i < 8; ++i) m = fmaxf(m, v[i]);
  for (int off = 32; off >= 1; off >>= 1) m = fmaxf(m, __shfl_xor(m, off, 64));
  if (lane == 0) redm[wave] = m;
  __syncthreads();
  m = fmaxf(fmaxf(redm[0], redm[1]), fmaxf(redm[2], redm[3]));
  float e[8], s = 0.f;
#pragma unroll
  for (int i = 0; i < 8; ++i) { e[i] = __expf(v[i] - m); s += e[i]; }
  for (int off = 32; off >= 1; off >>= 1) s += __shfl_xor(s, off, 64);
  if (lane == 0) reds[wave] = s;
  __syncthreads();
  s = reds[0] + reds[1] + reds[2] + reds[3];
  const float inv = 1.0f / s;
  uint4 o;
  o.x = (unsigned int)f2bf(e[0] * inv) | ((unsigned int)f2bf(e[1] * inv) << 16);
  o.y = (unsigned int)f2bf(e[2] * inv) | ((unsigned int)f2bf(e[3] * inv) << 16);
  o.z = (unsigned int)f2bf(e[4] * inv) | ((unsigned int)f2bf(e[5] * inv) << 16);
  o.w = (unsigned int)f2bf(e[6] * inv) | ((unsigned int)f2bf(e[7] * inv) << 16);
  *(uint4*)(S + base + tid * 8) = o;
}

extern "C" void kernel_launch(void* const* d_in, const int* in_sizes, int n_in,
                              void* d_out, int out_size, void* d_ws, size_t ws_size,
                              hipStream_t stream) {
  const float* q  = (const float*)d_in[0];
  const float* k  = (const float*)d_in[1];
  const float* v  = (const float*)d_in[2];
  const float* Wq = (const float*)d_in[3];
  const float* Wk = (const float*)d_in[4];
  const float* Wv = (const float*)d_in[5];
  const float* QA = (const float*)d_in[6];
  const float* QB = (const float*)d_in[7];
  const float* KA = (const float*)d_in[8];
  const float* KB = (const float*)d_in[9];
  const float* VA = (const float*)d_in[10];
  const float* VB = (const float*)d_in[11];
  const float* Wo = (const float*)d_in[12];

  unsigned short* W = (unsigned short*)d_ws;
  const long SEe = (long)8192 * 1024;  // 8388608
  unsigned short* qb  = W;             // dead after Q-proj -> scores low half
  unsigned short* kb  = W + SEe;
  unsigned short* vb  = W + 2 * SEe;   // dead after V-proj -> attn buffer
  unsigned short* Qp  = W + 3 * SEe;
  unsigned short* Kp  = W + 4 * SEe;
  unsigned short* VT  = W + 5 * SEe;   // [1024][8192] = V^T
  unsigned short* wqb = W + 6 * SEe;
  unsigned short* wkb = wqb + 1048576;
  unsigned short* wvb = wkb + 1048576;
  unsigned short* wob = wvb + 1048576;
  unsigned short* Bqb = wob + 1048576;
  unsigned short* Bkb = Bqb + 16384;
  unsigned short* Bvb = Bkb + 16384;
  unsigned short* Aqb = Bvb + 16384;
  unsigned short* Akb = Aqb + 16384;
  unsigned short* Avb = Akb + 16384;
  unsigned short* Tq  = Avb + 16384;   // [8192][16]
  unsigned short* Tk  = Tq + 131072;
  unsigned short* Tv  = Tk + 131072;
  unsigned short* scores = W;          // [4][2048][2048] bf16, aliases qb+kb
  unsigned short* attn   = vb;         // [8192][1024] bf16, aliases vb

  dim3 blk(256, 1, 1), blk5(512, 1, 1);
  prep_qkv<<<dim3(512, 3, 1), blk, 0, stream>>>(q, k, v, qb, kb, vb);
  cvt_all<<<dim3(512, 5, 1), blk, 0, stream>>>(Wq, Wk, Wv, Wo, QB, KB, VB, QA, KA, VA,
                                               wqb, wkb, wvb, wob, Bqb, Bkb, Bvb, Aqb, Akb, Avb);
  lora_t_mfma<<<dim3(128, 3, 1), blk, 0, stream>>>(qb, kb, vb, Aqb, Akb, Avb, Tq, Tk, Tv);

  // Q = qb@Wq^T + Tq@Bq^T ; K likewise (z batches; M=8192,N=1024,K=1024)
  gemm8p<true, false, true><<<dim3(4, 32, 2), blk5, 0, stream>>>(
      qb, wqb, Qp, Tq, Bqb, 1024, 1024, 1024, 1024, 1.0f,
      SEe, 1048576, SEe, 131072, 16384);
  // VT = Wv@vb^T + Bv@Tv^T  (M=1024,N=8192): OWNN, 128-tile -> 256 wg
  gemm128<true, false, false><<<dim3(32, 8, 1), blk5, 0, stream>>>(
      wvb, vb, VT, Bvb, Tv, 1024, 1024, 8192, 1024, 1.0f, 0, 0, 0, 0, 0);
  // scores = Qp@Kp^T / 32   (batched, M=N=2048,K=1024) -> 256 wg
  gemm8p<false, false, true><<<dim3(8, 8, 4), blk5, 0, stream>>>(
      Qp, Kp, scores, nullptr, nullptr, 1024, 1024, 2048, 1024, 0.03125f,
      (long)S_LEN * E_DIM, (long)S_LEN * E_DIM, (long)S_LEN * S_LEN, 0, 0);
  softmax_kernel<<<8192, blk, 0, stream>>>(scores);
  // attn_out = P@V = P@(VT)^T  (batched, M=2048,N=1024,K=2048), 128-tile -> 256 wg
  gemm128<false, false, true><<<dim3(4, 16, 4), blk5, 0, stream>>>(
      scores, VT, attn, nullptr, nullptr, 2048, 8192, 1024, 2048, 1.0f,
      (long)S_LEN * S_LEN, (long)S_LEN, (long)S_LEN * E_DIM, 0, 0);
  // final = attn@Wo^T -> fp32 d_out  (M=8192,N=1024,K=1024), 128-tile -> 256 wg
  gemm128<false, true, true><<<dim3(4, 64, 1), blk5, 0, stream>>>(
      attn, wob, d_out, nullptr, nullptr, 1024, 1024, 1024, 1024, 1.0f, 0, 0, 0, 0, 0);
}

// Round 8
// 360.685 us; speedup vs baseline: 1.2784x; 1.0273x over previous
//
#include <hip/hip_runtime.h>

// LoRA attention: B=4, S=2048, E=1024, R=16, fp32 in/out.
// R13 changes vs R12 (370.5us):
//  - R11/R12 all converge to ~600 TF chip-wide regardless of CU fill: the
//    per-phase {vmcnt+barrier -> ds_read -> lgkmcnt(0) -> MFMA} structure
//    exposes a full LDS round-trip per phase (reads drained in the same
//    inter-barrier region they're consumed in) and keeps both waves/SIMD in
//    the same role (no overlap for setprio to exploit).
//  - New schedule (m201-faithful read-ahead), 3 regions/K-tile:
//      R0: barrier; read aHi,b1f(cur); STAGE all of tile t+1 (nbf); Q00
//          (Q00 operands were read in prev tile's R2 -> latency crossed
//           a barrier and hid under Q11+barrier)
//      R1: barrier; Q10; Q01; vmcnt(4|3)  [self-portion AF0',BG0' landed]
//      R2: barrier; read aLo',b0f'(nbf); Q11; vmcnt(0) [~2 regions old]
//    All-waves landing guarantees: each half's vmcnt is >=1 barrier before
//    that half's first ds_read (vmcnt(4)@R1 + barrier@R2 -> R2 reads AF0',
//    BG0'; vmcnt(0)@R2 + barrier@R0 -> R0 reads AF1',BG1').
//    3 barriers/tile (was 4+), zero explicit lgkmcnt (compiler's
//    progressive counts), reads always >=1 region ahead of consumers.
//  - Per-wave vmcnt queues verified: gemm8p stages 8/tile at R0 only ->
//    vmcnt(4) retires AF0'+BG0', vmcnt(0) the rest; gemm128 stages 6 ->
//    vmcnt(3)/vmcnt(0). Dummy clamped stages on the last tile keep counts
//    uniform; trailing R2 reads of the dummy buffer are dead but harmless.
// Carried: XOR-swizzled row-major LDS (both sides), XCD swizzle, setprio
// around MFMA clusters, direct-register LoRA epilogue, R12 grids.

#define S_LEN 2048
#define E_DIM 1024

typedef __attribute__((ext_vector_type(8))) short short8;
typedef __attribute__((ext_vector_type(4))) float floatx4;

__device__ __forceinline__ unsigned short f2bf(float f) {
  union { float f; unsigned int u; } x; x.f = f;
  return (unsigned short)((x.u + 0x7fffu + ((x.u >> 16) & 1u)) >> 16);  // RNE
}
__device__ __forceinline__ float bf2f(unsigned short h) {
  union { unsigned int u; float f; } x; x.u = ((unsigned int)h) << 16;
  return x.f;
}

__device__ __forceinline__ void gld_lds16(const unsigned short* g, unsigned short* l) {
  __builtin_amdgcn_global_load_lds(
      (const __attribute__((address_space(1))) unsigned int*)(const void*)g,
      (__attribute__((address_space(3))) unsigned int*)(void*)l,
      16, 0, 0);
}

// ---------------- gemm8p: 256^2 tile, BK=64, read-ahead 3-region ----------
template<bool LORA, bool OUTF32, bool OWNM>
__global__ __launch_bounds__(512, 2) void gemm8p(
    const unsigned short* __restrict__ A, const unsigned short* __restrict__ B,
    void* __restrict__ Cv,
    const unsigned short* __restrict__ LA, const unsigned short* __restrict__ LB,
    long lda, long ldb, long ldc, int K, float scale,
    long batA, long batB, long batC, long batLA, long batLB) {
  __shared__ alignas(16) unsigned short As[2][2][8192];
  __shared__ alignas(16) unsigned short Bs[2][2][8192];

  const int tid  = threadIdx.x;
  const int wave = tid >> 6, lane = tid & 63;
  const int quad = lane >> 4, l16 = lane & 15;
  const int wr = wave >> 2, wc = wave & 3;  // 2M x 4N waves, each 128x64

  const int Nx = (int)gridDim.x, Ny = (int)gridDim.y;
  const int wg2 = (int)blockIdx.x + Nx * (int)blockIdx.y;
  const int xcd = wg2 & 7, ii = wg2 >> 3;
  int bx, by;
  if constexpr (OWNM) {
    const int lg = 31 - __clz(Nx);
    by = xcd * (Ny >> 3) + (ii >> lg);
    bx = ii & (Nx - 1);
  } else {
    const int lg = 31 - __clz(Ny);
    bx = xcd * (Nx >> 3) + (ii >> lg);
    by = ii & (Ny - 1);
  }
  const long m0 = (long)by * 256;
  const long n0 = (long)bx * 256;
  const unsigned short* Az = A + (long)blockIdx.z * batA;
  const unsigned short* Bz = B + (long)blockIdx.z * batB;

  floatx4 acc[8][4];
#pragma unroll
  for (int i = 0; i < 8; ++i)
#pragma unroll
    for (int j = 0; j < 4; ++j) acc[i][j] = (floatx4){0.f, 0.f, 0.f, 0.f};

  const int lr = tid >> 3;                 // 0..63 (chunk2: +64)
  const int sp = (tid & 7) ^ (lr & 7);     // inverse-swizzled source slot
  const unsigned short* aS = Az + (m0 + lr) * lda + sp * 8;
  const unsigned short* bS = Bz + (n0 + (lr >> 5) * 64 + (lr & 31)) * ldb + sp * 8;

  // stage order per tile: AF0(2), BG0(2), AF1(2), BG1(2) -> 8 loads
#define STAGE8(bf, k0)                                                       \
  do {                                                                       \
    gld_lds16(aS + (k0), &As[bf][0][tid * 8]);                               \
    gld_lds16(aS + (long)128 * lda + (k0), &As[bf][0][4096 + tid * 8]);      \
    gld_lds16(bS + (k0), &Bs[bf][0][tid * 8]);                               \
    gld_lds16(bS + (long)128 * ldb + (k0), &Bs[bf][0][4096 + tid * 8]);      \
    gld_lds16(aS + (long)64 * lda + (k0), &As[bf][1][tid * 8]);              \
    gld_lds16(aS + (long)192 * lda + (k0), &As[bf][1][4096 + tid * 8]);      \
    gld_lds16(bS + (long)32 * ldb + (k0), &Bs[bf][1][tid * 8]);              \
    gld_lds16(bS + (long)160 * ldb + (k0), &Bs[bf][1][4096 + tid * 8]);      \
  } while (0)

  const int xo    = (l16 & 7) << 4;
  const int aoff0 = ((quad * 16) ^ xo) >> 1;
  const int aoff1 = ((64 + quad * 16) ^ xo) >> 1;
  const int arow  = wr * 4096 + l16 * 64;
  const int brow  = wc * 2048 + l16 * 64;

  short8 aLo[4][2], aHi[4][2], b0f[2][2], b1f[2][2];

#define READ_ALO(bf)                                                         \
  do {                                                                       \
    _Pragma("unroll") for (int i = 0; i < 4; ++i) {                          \
      aLo[i][0] = *(const short8*)&As[bf][0][arow + i * 1024 + aoff0];       \
      aLo[i][1] = *(const short8*)&As[bf][0][arow + i * 1024 + aoff1];       \
    }                                                                        \
  } while (0)
#define READ_AHI(bf)                                                         \
  do {                                                                       \
    _Pragma("unroll") for (int i = 0; i < 4; ++i) {                          \
      aHi[i][0] = *(const short8*)&As[bf][1][arow + i * 1024 + aoff0];       \
      aHi[i][1] = *(const short8*)&As[bf][1][arow + i * 1024 + aoff1];       \
    }                                                                        \
  } while (0)
#define READ_B0(bf)                                                          \
  do {                                                                       \
    _Pragma("unroll") for (int j = 0; j < 2; ++j) {                          \
      b0f[j][0] = *(const short8*)&Bs[bf][0][brow + j * 1024 + aoff0];       \
      b0f[j][1] = *(const short8*)&Bs[bf][0][brow + j * 1024 + aoff1];       \
    }                                                                        \
  } while (0)
#define READ_B1(bf)                                                          \
  do {                                                                       \
    _Pragma("unroll") for (int j = 0; j < 2; ++j) {                          \
      b1f[j][0] = *(const short8*)&Bs[bf][1][brow + j * 1024 + aoff0];       \
      b1f[j][1] = *(const short8*)&Bs[bf][1][brow + j * 1024 + aoff1];       \
    }                                                                        \
  } while (0)
#define QUAD(am, bm, io, jo)                                                 \
  do {                                                                       \
    _Pragma("unroll") for (int ks = 0; ks < 2; ++ks)                         \
      _Pragma("unroll") for (int i = 0; i < 4; ++i)                          \
        _Pragma("unroll") for (int j = 0; j < 2; ++j)                        \
          acc[i + (io)][j + (jo)] = __builtin_amdgcn_mfma_f32_16x16x32_bf16( \
              am[i][ks], bm[j][ks], acc[i + (io)][j + (jo)], 0, 0, 0);       \
  } while (0)

  // prologue: tile 0 staged, full drain (one-time), read Q00 operands.
  STAGE8(0, 0);
  asm volatile("s_waitcnt vmcnt(0)\n\ts_barrier" ::: "memory");
  READ_ALO(0); READ_B0(0);

  const int NT = K >> 6;
  for (int t = 0; t < NT; ++t) {
    const int cur = t & 1, nbf = cur ^ 1;
    const int kN = (t + 1 < NT ? t + 1 : NT - 1) << 6;

    // ---- R0: read remaining cur halves, stage ALL of tile t+1, Q00
    asm volatile("s_barrier" ::: "memory");
    READ_AHI(cur); READ_B1(cur);
    STAGE8(nbf, kN);
    __builtin_amdgcn_s_setprio(1);
    QUAD(aLo, b0f, 0, 0);
    __builtin_amdgcn_s_setprio(0);

    // ---- R1: pure MFMA, then self-wait for AF0',BG0'
    asm volatile("s_barrier" ::: "memory");
    __builtin_amdgcn_s_setprio(1);
    QUAD(aHi, b0f, 4, 0);
    QUAD(aLo, b1f, 0, 2);
    __builtin_amdgcn_s_setprio(0);
    asm volatile("s_waitcnt vmcnt(4)" ::: "memory");

    // ---- R2: read next tile's Q00 operands (AF0',BG0' all-waves safe:
    //          vmcnt(4)@R1 + this barrier), Q11, self-wait rest.
    asm volatile("s_barrier" ::: "memory");
    READ_ALO(nbf); READ_B0(nbf);
    __builtin_amdgcn_s_setprio(1);
    QUAD(aHi, b1f, 4, 2);
    __builtin_amdgcn_s_setprio(0);
    asm volatile("s_waitcnt vmcnt(0)" ::: "memory");
  }

  if constexpr (LORA) {
    const unsigned short* LAz = LA + (long)blockIdx.z * batLA;
    const unsigned short* LBz = LB + (long)blockIdx.z * batLB;
    const short8 z8 = {0, 0, 0, 0, 0, 0, 0, 0};
    short8 b2[4];
#pragma unroll
    for (int j = 0; j < 4; ++j) {
      const long row = n0 + wc * 64 + j * 16 + l16;
      b2[j] = (quad < 2) ? *(const short8*)(LBz + row * 16 + quad * 8) : z8;
    }
#pragma unroll
    for (int i = 0; i < 8; ++i) {
      const long row = m0 + wr * 128 + i * 16 + l16;
      const short8 a2 =
          (quad < 2) ? *(const short8*)(LAz + row * 16 + quad * 8) : z8;
#pragma unroll
      for (int j = 0; j < 4; ++j)
        acc[i][j] = __builtin_amdgcn_mfma_f32_16x16x32_bf16(a2, b2[j], acc[i][j], 0, 0, 0);
    }
  }

#pragma unroll
  for (int i = 0; i < 8; ++i) {
    const long row = m0 + wr * 128 + i * 16 + quad * 4;
#pragma unroll
    for (int j = 0; j < 4; ++j) {
      const long col = n0 + wc * 64 + j * 16 + l16;
#pragma unroll
      for (int rr = 0; rr < 4; ++rr) {
        float val = acc[i][j][rr] * scale;
        if constexpr (OUTF32)
          ((float*)Cv)[(long)blockIdx.z * batC + (row + rr) * ldc + col] = val;
        else
          ((unsigned short*)Cv)[(long)blockIdx.z * batC + (row + rr) * ldc + col] = f2bf(val);
      }
    }
  }
#undef STAGE8
#undef READ_ALO
#undef READ_AHI
#undef READ_B0
#undef READ_B1
#undef QUAD
}

// ---------------- gemm128: 128x256 tile, BK=64, read-ahead 3-region -------
template<bool LORA, bool OUTF32, bool OWNM>
__global__ __launch_bounds__(512, 2) void gemm128(
    const unsigned short* __restrict__ A, const unsigned short* __restrict__ B,
    void* __restrict__ Cv,
    const unsigned short* __restrict__ LA, const unsigned short* __restrict__ LB,
    long lda, long ldb, long ldc, int K, float scale,
    long batA, long batB, long batC, long batLA, long batLB) {
  __shared__ alignas(16) unsigned short As[2][2][4096];  // [buf][half][64x64]
  __shared__ alignas(16) unsigned short Bs[2][2][8192];  // [buf][half][128x64]

  const int tid  = threadIdx.x;
  const int wave = tid >> 6, lane = tid & 63;
  const int quad = lane >> 4, l16 = lane & 15;
  const int wr = wave >> 2, wc = wave & 3;  // 2M x 4N waves, each 64x64

  const int Nx = (int)gridDim.x, Ny = (int)gridDim.y;
  const int wg2 = (int)blockIdx.x + Nx * (int)blockIdx.y;
  const int xcd = wg2 & 7, ii = wg2 >> 3;
  int bx, by;
  if constexpr (OWNM) {
    const int lg = 31 - __clz(Nx);
    by = xcd * (Ny >> 3) + (ii >> lg);
    bx = ii & (Nx - 1);
  } else {
    const int lg = 31 - __clz(Ny);
    bx = xcd * (Nx >> 3) + (ii >> lg);
    by = ii & (Ny - 1);
  }
  const long m0 = (long)by * 128;
  const long n0 = (long)bx * 256;
  const unsigned short* Az = A + (long)blockIdx.z * batA;
  const unsigned short* Bz = B + (long)blockIdx.z * batB;

  floatx4 acc[4][4];
#pragma unroll
  for (int i = 0; i < 4; ++i)
#pragma unroll
    for (int j = 0; j < 4; ++j) acc[i][j] = (floatx4){0.f, 0.f, 0.f, 0.f};

  const int lr = tid >> 3;
  const int sp = (tid & 7) ^ (lr & 7);
  const unsigned short* aS = Az + (m0 + (lr >> 5) * 64 + (lr & 31)) * lda + sp * 8;
  const unsigned short* bS  = Bz + (n0 + (lr >> 5) * 64 + (lr & 31)) * ldb + sp * 8;
  const unsigned short* bS2 = Bz + (n0 + ((lr + 64) >> 5) * 64 + ((lr + 64) & 31)) * ldb + sp * 8;

  // stage order per tile: AF0(1), BG0(2), AF1(1), BG1(2) -> 6 loads
#define STAGE6(bf, k0)                                                       \
  do {                                                                       \
    gld_lds16(aS + (k0), &As[bf][0][tid * 8]);                               \
    gld_lds16(bS + (k0), &Bs[bf][0][tid * 8]);                               \
    gld_lds16(bS2 + (k0), &Bs[bf][0][4096 + tid * 8]);                       \
    gld_lds16(aS + (long)32 * lda + (k0), &As[bf][1][tid * 8]);              \
    gld_lds16(bS + (long)32 * ldb + (k0), &Bs[bf][1][tid * 8]);              \
    gld_lds16(bS2 + (long)32 * ldb + (k0), &Bs[bf][1][4096 + tid * 8]);      \
  } while (0)

  const int xo    = (l16 & 7) << 4;
  const int aoff0 = ((quad * 16) ^ xo) >> 1;
  const int aoff1 = ((64 + quad * 16) ^ xo) >> 1;
  const int arow  = wr * 2048 + l16 * 64;
  const int brow  = wc * 2048 + l16 * 64;

  short8 aF0[2][2], aF1[2][2], bG0[2][2], bG1[2][2];

#define READ_AF(ar, h)                                                       \
  do {                                                                       \
    _Pragma("unroll") for (int i = 0; i < 2; ++i) {                          \
      ar[i][0] = *(const short8*)&As[bf_][h][arow + i * 1024 + aoff0];       \
      ar[i][1] = *(const short8*)&As[bf_][h][arow + i * 1024 + aoff1];       \
    }                                                                        \
  } while (0)
#define READ_BG(br, h)                                                       \
  do {                                                                       \
    _Pragma("unroll") for (int j = 0; j < 2; ++j) {                          \
      br[j][0] = *(const short8*)&Bs[bf_][h][brow + j * 1024 + aoff0];       \
      br[j][1] = *(const short8*)&Bs[bf_][h][brow + j * 1024 + aoff1];       \
    }                                                                        \
  } while (0)
#define QUAD(am, bm, io, jo)                                                 \
  do {                                                                       \
    _Pragma("unroll") for (int ks = 0; ks < 2; ++ks)                         \
      _Pragma("unroll") for (int i = 0; i < 2; ++i)                          \
        _Pragma("unroll") for (int j = 0; j < 2; ++j)                        \
          acc[i + (io)][j + (jo)] = __builtin_amdgcn_mfma_f32_16x16x32_bf16( \
              am[i][ks], bm[j][ks], acc[i + (io)][j + (jo)], 0, 0, 0);       \
  } while (0)

  STAGE6(0, 0);
  asm volatile("s_waitcnt vmcnt(0)\n\ts_barrier" ::: "memory");
  { const int bf_ = 0; READ_AF(aF0, 0); READ_BG(bG0, 0); }

  const int NT = K >> 6;
  for (int t = 0; t < NT; ++t) {
    const int cur = t & 1, nbf = cur ^ 1;
    const int kN = (t + 1 < NT ? t + 1 : NT - 1) << 6;

    // ---- R0
    asm volatile("s_barrier" ::: "memory");
    { const int bf_ = cur; READ_AF(aF1, 1); READ_BG(bG1, 1); }
    STAGE6(nbf, kN);
    __builtin_amdgcn_s_setprio(1);
    QUAD(aF0, bG0, 0, 0);
    __builtin_amdgcn_s_setprio(0);

    // ---- R1
    asm volatile("s_barrier" ::: "memory");
    __builtin_amdgcn_s_setprio(1);
    QUAD(aF1, bG0, 2, 0);
    QUAD(aF0, bG1, 0, 2);
    __builtin_amdgcn_s_setprio(0);
    asm volatile("s_waitcnt vmcnt(3)" ::: "memory");

    // ---- R2
    asm volatile("s_barrier" ::: "memory");
    { const int bf_ = nbf; READ_AF(aF0, 0); READ_BG(bG0, 0); }
    __builtin_amdgcn_s_setprio(1);
    QUAD(aF1, bG1, 2, 2);
    __builtin_amdgcn_s_setprio(0);
    asm volatile("s_waitcnt vmcnt(0)" ::: "memory");
  }

  if constexpr (LORA) {
    const unsigned short* LAz = LA + (long)blockIdx.z * batLA;
    const unsigned short* LBz = LB + (long)blockIdx.z * batLB;
    const short8 z8 = {0, 0, 0, 0, 0, 0, 0, 0};
    short8 b2[4];
#pragma unroll
    for (int j = 0; j < 4; ++j) {
      const long row = n0 + wc * 64 + j * 16 + l16;
      b2[j] = (quad < 2) ? *(const short8*)(LBz + row * 16 + quad * 8) : z8;
    }
#pragma unroll
    for (int i = 0; i < 4; ++i) {
      const long row = m0 + wr * 64 + i * 16 + l16;
      const short8 a2 =
          (quad < 2) ? *(const short8*)(LAz + row * 16 + quad * 8) : z8;
#pragma unroll
      for (int j = 0; j < 4; ++j)
        acc[i][j] = __builtin_amdgcn_mfma_f32_16x16x32_bf16(a2, b2[j], acc[i][j], 0, 0, 0);
    }
  }

#pragma unroll
  for (int i = 0; i < 4; ++i) {
    const long row = m0 + wr * 64 + i * 16 + quad * 4;
#pragma unroll
    for (int j = 0; j < 4; ++j) {
      const long col = n0 + wc * 64 + j * 16 + l16;
#pragma unroll
      for (int rr = 0; rr < 4; ++rr) {
        float val = acc[i][j][rr] * scale;
        if constexpr (OUTF32)
          ((float*)Cv)[(long)blockIdx.z * batC + (row + rr) * ldc + col] = val;
        else
          ((unsigned short*)Cv)[(long)blockIdx.z * batC + (row + rr) * ldc + col] = f2bf(val);
      }
    }
  }
#undef STAGE6
#undef READ_AF
#undef READ_BG
#undef QUAD
}

__device__ __forceinline__ uint4 pack8(const float* x) {
  float4 a = *(const float4*)x;
  float4 b = *(const float4*)(x + 4);
  uint4 o;
  o.x = (unsigned int)f2bf(a.x) | ((unsigned int)f2bf(a.y) << 16);
  o.y = (unsigned int)f2bf(a.z) | ((unsigned int)f2bf(a.w) << 16);
  o.z = (unsigned int)f2bf(b.x) | ((unsigned int)f2bf(b.y) << 16);
  o.w = (unsigned int)f2bf(b.z) | ((unsigned int)f2bf(b.w) << 16);
  return o;
}

// pure fp32->bf16 convert of q/k/v. grid (512, 3), 16384 elems/block.
__global__ __launch_bounds__(256) void prep_qkv(
    const float* __restrict__ q, const float* __restrict__ k, const float* __restrict__ v,
    unsigned short* __restrict__ qb, unsigned short* __restrict__ kb,
    unsigned short* __restrict__ vb) {
  const float* X; unsigned short* Y;
  if (blockIdx.y == 0)      { X = q; Y = qb; }
  else if (blockIdx.y == 1) { X = k; Y = kb; }
  else                      { X = v; Y = vb; }
  const int tid = threadIdx.x;
  const long blk = (long)blockIdx.x * 16384;
#pragma unroll
  for (int it = 0; it < 8; ++it) {
    const long idx = blk + it * 2048 + tid * 8;
    *(uint4*)(Y + idx) = pack8(X + idx);
  }
}

// all weight converts in one dispatch. grid (512, 5).
__global__ __launch_bounds__(256) void cvt_all(
    const float* __restrict__ Wq, const float* __restrict__ Wk,
    const float* __restrict__ Wv, const float* __restrict__ Wo,
    const float* __restrict__ QB, const float* __restrict__ KB, const float* __restrict__ VB,
    const float* __restrict__ QA, const float* __restrict__ KA, const float* __restrict__ VA,
    unsigned short* __restrict__ wqb, unsigned short* __restrict__ wkb,
    unsigned short* __restrict__ wvb, unsigned short* __restrict__ wob,
    unsigned short* __restrict__ Bqb, unsigned short* __restrict__ Bkb, unsigned short* __restrict__ Bvb,
    unsigned short* __restrict__ Aqb, unsigned short* __restrict__ Akb, unsigned short* __restrict__ Avb) {
  if (blockIdx.y < 4) {
    const float* x; unsigned short* y;
    switch (blockIdx.y) {
      case 0: x = Wq; y = wqb; break;
      case 1: x = Wk; y = wkb; break;
      case 2: x = Wv; y = wvb; break;
      default: x = Wo; y = wob; break;
    }
    const long i = ((long)blockIdx.x * 256 + threadIdx.x) * 8;
    *(uint4*)(y + i) = pack8(x + i);
  } else {
    if (blockIdx.x >= 48) return;
    const int mat = blockIdx.x >> 3, sub = blockIdx.x & 7;
    const float* x; unsigned short* y;
    switch (mat) {
      case 0: x = QB; y = Bqb; break;
      case 1: x = KB; y = Bkb; break;
      case 2: x = VB; y = Bvb; break;
      case 3: x = QA; y = Aqb; break;
      case 4: x = KA; y = Akb; break;
      default: x = VA; y = Avb; break;
    }
    const long i = ((long)sub * 256 + threadIdx.x) * 8;
    *(uint4*)(y + i) = pack8(x + i);
  }
}

// T[8192][16] = Xb @ Am^T via MFMA. grid (128, 3): 64 rows/block, 16/wave.
__global__ __launch_bounds__(256) void lora_t_mfma(
    const unsigned short* __restrict__ qb, const unsigned short* __restrict__ kb,
    const unsigned short* __restrict__ vb,
    const unsigned short* __restrict__ Aq, const unsigned short* __restrict__ Ak,
    const unsigned short* __restrict__ Av,
    unsigned short* __restrict__ Tq, unsigned short* __restrict__ Tk,
    unsigned short* __restrict__ Tv) {
  const unsigned short* X; const unsigned short* Am; unsigned short* T;
  if (blockIdx.y == 0)      { X = qb; Am = Aq; T = Tq; }
  else if (blockIdx.y == 1) { X = kb; Am = Ak; T = Tk; }
  else                      { X = vb; Am = Av; T = Tv; }
  const int tid = threadIdx.x, wave = tid >> 6, lane = tid & 63;
  const int quad = lane >> 4, l16 = lane & 15;
  const long m0 = (long)blockIdx.x * 64 + wave * 16;
  floatx4 acc = (floatx4){0.f, 0.f, 0.f, 0.f};
  const unsigned short* xp = X + (m0 + l16) * 1024 + quad * 8;
  const unsigned short* ap = Am + (long)l16 * 1024 + quad * 8;
#pragma unroll 4
  for (int k0 = 0; k0 < 1024; k0 += 32) {
    short8 af = *(const short8*)(xp + k0);
    short8 bf = *(const short8*)(ap + k0);
    acc = __builtin_amdgcn_mfma_f32_16x16x32_bf16(af, bf, acc, 0, 0, 0);
  }
#pragma unroll
  for (int rr = 0; rr < 4; ++rr)
    T[(m0 + quad * 4 + rr) * 16 + l16] = f2bf(acc[rr]);
}

// in-place row softmax over 2048 bf16 scores; one block per row
__global__ __launch_bounds__(256) void softmax_kernel(unsigned short* __restrict__ S) {
  const long base = (long)blockIdx.x * 2048;
  const int tid = threadIdx.x;
  const int lane = tid & 63, wave = tid >> 6;
  __shared__ float redm[4], reds[4];
  uint4 raw = *(const uint4*)(S + base + tid * 8);
  unsigned int w[4] = {raw.x, raw.y, raw.z, raw.w};
  float v[8];
#pragma unroll
  for (int i = 0; i < 4; ++i) {
    v[2 * i]     = bf2f((unsigned short)(w[i] & 0xffffu));
    v[2 * i + 1] = bf2f((unsigned short)(w[i] >> 16));
  }
  float m = v[0];
#pragma unroll
  for (int i = 1; i < 8; ++i) m = fmaxf(m, v[i]);
  for (int off = 32; off >= 1; off >>= 1) m = fmaxf(m, __shfl_xor(m, off, 64));
  if (lane == 0) redm[wave] = m;
  __syncthreads();
  m = fmaxf(fmaxf(redm[0], redm[1]), fmaxf(redm[2], redm[3]));
  float e[8], s = 0.f;
#pragma unroll
  for (int i = 0; i < 8; ++i) { e[i] = __expf(v[i] - m); s += e[i]; }
  for (int off = 32; off >= 1; off >>= 1) s += __shfl_xor(s, off, 64);
  if (lane == 0) reds[wave] = s;
  __syncthreads();
  s = reds[0] + reds[1] + reds[2] + reds[3];
  const float inv = 1.0f / s;
  uint4 o;
  o.x = (unsigned int)f2bf(e[0] * inv) | ((unsigned int)f2bf(e[1] * inv) << 16);
  o.y = (unsigned int)f2bf(e[2] * inv) | ((unsigned int)f2bf(e[3] * inv) << 16);
  o.z = (unsigned int)f2bf(e[4] * inv) | ((unsigned int)f2bf(e[5] * inv) << 16);
  o.w = (unsigned int)f2bf(e[6] * inv) | ((unsigned int)f2bf(e[7] * inv) << 16);
  *(uint4*)(S + base + tid * 8) = o;
}

extern "C" void kernel_launch(void* const* d_in, const int* in_sizes, int n_in,
                              void* d_out, int out_size, void* d_ws, size_t ws_size,
                              hipStream_t stream) {
  const float* q  = (const float*)d_in[0];
  const float* k  = (const float*)d_in[1];
  const float* v  = (const float*)d_in[2];
  const float* Wq = (const float*)d_in[3];
  const float* Wk = (const float*)d_in[4];
  const float* Wv = (const float*)d_in[5];
  const float* QA = (const float*)d_in[6];
  const float* QB = (const float*)d_in[7];
  const float* KA = (const float*)d_in[8];
  const float* KB = (const float*)d_in[9];
  const float* VA = (const float*)d_in[10];
  const float* VB = (const float*)d_in[11];
  const float* Wo = (const float*)d_in[12];

  unsigned short* W = (unsigned short*)d_ws;
  const long SEe = (long)8192 * 1024;  // 8388608
  unsigned short* qb  = W;             // dead after Q-proj -> scores low half
  unsigned short* kb  = W + SEe;
  unsigned short* vb  = W + 2 * SEe;   // dead after V-proj -> attn buffer
  unsigned short* Qp  = W + 3 * SEe;
  unsigned short* Kp  = W + 4 * SEe;
  unsigned short* VT  = W + 5 * SEe;   // [1024][8192] = V^T
  unsigned short* wqb = W + 6 * SEe;
  unsigned short* wkb = wqb + 1048576;
  unsigned short* wvb = wkb + 1048576;
  unsigned short* wob = wvb + 1048576;
  unsigned short* Bqb = wob + 1048576;
  unsigned short* Bkb = Bqb + 16384;
  unsigned short* Bvb = Bkb + 16384;
  unsigned short* Aqb = Bvb + 16384;
  unsigned short* Akb = Aqb + 16384;
  unsigned short* Avb = Akb + 16384;
  unsigned short* Tq  = Avb + 16384;   // [8192][16]
  unsigned short* Tk  = Tq + 131072;
  unsigned short* Tv  = Tk + 131072;
  unsigned short* scores = W;          // [4][2048][2048] bf16, aliases qb+kb
  unsigned short* attn   = vb;         // [8192][1024] bf16, aliases vb

  dim3 blk(256, 1, 1), blk5(512, 1, 1);
  prep_qkv<<<dim3(512, 3, 1), blk, 0, stream>>>(q, k, v, qb, kb, vb);
  cvt_all<<<dim3(512, 5, 1), blk, 0, stream>>>(Wq, Wk, Wv, Wo, QB, KB, VB, QA, KA, VA,
                                               wqb, wkb, wvb, wob, Bqb, Bkb, Bvb, Aqb, Akb, Avb);
  lora_t_mfma<<<dim3(128, 3, 1), blk, 0, stream>>>(qb, kb, vb, Aqb, Akb, Avb, Tq, Tk, Tv);

  // Q = qb@Wq^T + Tq@Bq^T ; K likewise (z batches; M=8192,N=1024,K=1024)
  gemm8p<true, false, true><<<dim3(4, 32, 2), blk5, 0, stream>>>(
      qb, wqb, Qp, Tq, Bqb, 1024, 1024, 1024, 1024, 1.0f,
      SEe, 1048576, SEe, 131072, 16384);
  // VT = Wv@vb^T + Bv@Tv^T  (M=1024,N=8192): OWNN, 128-tile -> 256 wg
  gemm128<true, false, false><<<dim3(32, 8, 1), blk5, 0, stream>>>(
      wvb, vb, VT, Bvb, Tv, 1024, 1024, 8192, 1024, 1.0f, 0, 0, 0, 0, 0);
  // scores = Qp@Kp^T / 32   (batched, M=N=2048,K=1024) -> 256 wg
  gemm8p<false, false, true><<<dim3(8, 8, 4), blk5, 0, stream>>>(
      Qp, Kp, scores, nullptr, nullptr, 1024, 1024, 2048, 1024, 0.03125f,
      (long)S_LEN * E_DIM, (long)S_LEN * E_DIM, (long)S_LEN * S_LEN, 0, 0);
  softmax_kernel<<<8192, blk, 0, stream>>>(scores);
  // attn_out = P@V = P@(VT)^T  (batched, M=2048,N=1024,K=2048), 128-tile -> 256 wg
  gemm128<false, false, true><<<dim3(4, 16, 4), blk5, 0, stream>>>(
      scores, VT, attn, nullptr, nullptr, 2048, 8192, 1024, 2048, 1.0f,
      (long)S_LEN * S_LEN, (long)S_LEN, (long)S_LEN * E_DIM, 0, 0);
  // final = attn@Wo^T -> fp32 d_out  (M=8192,N=1024,K=1024), 128-tile -> 256 wg
  gemm128<false, true, true><<<dim3(4, 64, 1), blk5, 0, stream>>>(
      attn, wob, d_out, nullptr, nullptr, 1024, 1024, 1024, 1024, 1.0f, 0, 0, 0, 0, 0);
}